// Round 1
// baseline (3108.616 us; speedup 1.0000x reference)
//
#include <hip/hip_runtime.h>
#include <math.h>

// Problem constants
#define Lnum 3
#define Mdim 4096
#define Pdim 4
#define Gdim 4
#define NIN 8192
#define NOUT 1000
#define Bdim 2048
#define Fdim 6
#define CIN 2048      // input channels per group (all layers)
#define MG 1024       // M / G
#define CH 2048       // M / K
#define DNEXT 8192    // M/K * P  (== NIN, so row stride is 8192 for every layer input)

// GEMM tiling
#define BM 64
#define BN 64
#define BK 16
#define RCHUNK 128    // rows per bn_stats block
#define NRCHUNK (Bdim / RCHUNK)   // 16

// ---------------------------------------------------------------------------
// Grouped GEMM: Y[b, m*G+g] = sum_c H[b, c*G+g] * W[g, m, c] + bias[g, m]
// H row stride = 8192 (true for x and for intermediate h).
// ---------------------------------------------------------------------------
__global__ __launch_bounds__(256) void gemm_grouped(
    const float* __restrict__ H,   // (B, 8192)
    const float* __restrict__ Wl,  // (G, MG, CIN) this layer
    const float* __restrict__ bl,  // (G, MG)
    float* __restrict__ Y)         // (B, M)
{
    const int g  = blockIdx.z;
    const int m0 = blockIdx.x * BN;
    const int b0 = blockIdx.y * BM;

    __shared__ float As[BK][BM + 4];
    __shared__ float Bs[BK][BN + 4];

    const int tid = threadIdx.x;
    const int tx = tid & 15;    // 0..15 -> output col group
    const int ty = tid >> 4;    // 0..15 -> output row group

    float acc[4][4] = {};
    const float* Wg = Wl + (size_t)g * MG * CIN;

    for (int k0 = 0; k0 < CIN; k0 += BK) {
#pragma unroll
        for (int q = 0; q < 4; ++q) {
            int idx = tid + q * 256;
            int c = idx & (BK - 1);
            int r = idx >> 4;
            As[c][r] = H[(size_t)(b0 + r) * NIN + (size_t)(k0 + c) * Gdim + g];
        }
#pragma unroll
        for (int q = 0; q < 4; ++q) {
            int idx = tid + q * 256;
            int c = idx & (BK - 1);
            int r = idx >> 4;
            Bs[c][r] = Wg[(size_t)(m0 + r) * CIN + (k0 + c)];
        }
        __syncthreads();
#pragma unroll
        for (int c = 0; c < BK; ++c) {
            const float4 a4 = *reinterpret_cast<const float4*>(&As[c][ty * 4]);
            const float4 b4 = *reinterpret_cast<const float4*>(&Bs[c][tx * 4]);
            acc[0][0] += a4.x * b4.x; acc[0][1] += a4.x * b4.y; acc[0][2] += a4.x * b4.z; acc[0][3] += a4.x * b4.w;
            acc[1][0] += a4.y * b4.x; acc[1][1] += a4.y * b4.y; acc[1][2] += a4.y * b4.z; acc[1][3] += a4.y * b4.w;
            acc[2][0] += a4.z * b4.x; acc[2][1] += a4.z * b4.y; acc[2][2] += a4.z * b4.z; acc[2][3] += a4.z * b4.w;
            acc[3][0] += a4.w * b4.x; acc[3][1] += a4.w * b4.y; acc[3][2] += a4.w * b4.z; acc[3][3] += a4.w * b4.w;
        }
        __syncthreads();
    }

#pragma unroll
    for (int i = 0; i < 4; ++i) {
        const int bb = b0 + ty * 4 + i;
#pragma unroll
        for (int j = 0; j < 4; ++j) {
            const int m = m0 + tx * 4 + j;
            Y[(size_t)bb * Mdim + m * Gdim + g] = acc[i][j] + bl[g * MG + m];
        }
    }
}

// ---------------------------------------------------------------------------
// BatchNorm stats, deterministic two stage
// ---------------------------------------------------------------------------
__global__ __launch_bounds__(256) void bn_stats(
    const float* __restrict__ Y, float* __restrict__ psum, float* __restrict__ psumsq)
{
    const int j  = blockIdx.x * 256 + threadIdx.x;   // column
    const int r0 = blockIdx.y * RCHUNK;
    float s = 0.f, ss = 0.f;
    for (int r = 0; r < RCHUNK; ++r) {
        float v = Y[(size_t)(r0 + r) * Mdim + j];
        s += v; ss += v * v;
    }
    psum[blockIdx.y * Mdim + j]   = s;
    psumsq[blockIdx.y * Mdim + j] = ss;
}

__global__ __launch_bounds__(256) void bn_finalize(
    const float* __restrict__ psum, const float* __restrict__ psumsq,
    const float* __restrict__ gamma, const float* __restrict__ beta,
    float* __restrict__ scale, float* __restrict__ shift)
{
    const int j = blockIdx.x * 256 + threadIdx.x;
    if (j >= Mdim) return;
    float s = 0.f, ss = 0.f;
    for (int r = 0; r < NRCHUNK; ++r) {
        s  += psum[r * Mdim + j];
        ss += psumsq[r * Mdim + j];
    }
    const float mu  = s * (1.f / Bdim);
    const float var = ss * (1.f / Bdim) - mu * mu;
    const float sc  = gamma[j] * rsqrtf(var + 1e-5f);
    scale[j] = sc;
    shift[j] = beta[j] - mu * sc;
}

// ---------------------------------------------------------------------------
// softmax over alpha (L*P rows of F) -> wsm
// ---------------------------------------------------------------------------
__global__ void alpha_softmax(const float* __restrict__ alpha, float* __restrict__ wsm)
{
    const int idx = threadIdx.x;
    if (idx >= Lnum * Pdim) return;
    const float* a = alpha + idx * Fdim;
    float mx = a[0];
#pragma unroll
    for (int f = 1; f < Fdim; ++f) mx = fmaxf(mx, a[f]);
    float e[Fdim]; float s = 0.f;
#pragma unroll
    for (int f = 0; f < Fdim; ++f) { e[f] = __expf(a[f] - mx); s += e[f]; }
    const float inv = 1.f / s;
#pragma unroll
    for (int f = 0; f < Fdim; ++f) wsm[idx * Fdim + f] = e[f] * inv;
}

// ---------------------------------------------------------------------------
// Fused normalize + permutation gather + combinact (K=2 closed form)
// Hout[b, p*CH + c] = sum_f w[p,f] * act_f( z0, z1 ),
//   z_k = ynorm[b, perm[p, c*2+k]]
// ---------------------------------------------------------------------------
__global__ __launch_bounds__(256) void combinact_kernel(
    const float* __restrict__ Y, const float* __restrict__ scale,
    const float* __restrict__ shift, const int* __restrict__ perm, // (P, M)
    const float* __restrict__ wsm,                                  // (P, F)
    float* __restrict__ Hout)                                       // (B, 8192)
{
    const int c = blockIdx.x * 256 + threadIdx.x;   // 0..CH-1
    const int b = blockIdx.y;
    const float* yr = Y + (size_t)b * Mdim;

    float outv[Pdim];
#pragma unroll
    for (int p = 0; p < Pdim; ++p) {
        const int j0 = perm[p * Mdim + c * 2];
        const int j1 = perm[p * Mdim + c * 2 + 1];
        const float z0 = yr[j0] * scale[j0] + shift[j0];
        const float z1 = yr[j1] * scale[j1] + shift[j1];

        const float mx  = fmaxf(z0, z1);
        const float pr  = z0 * z1;
        const float sgn = (pr > 0.f) ? 1.f : ((pr < 0.f) ? -1.f : 0.f);
        const float a1  = sgn * sqrtf(fabsf(pr) + 1e-12f);
        const float s0  = 1.f / (1.f + __expf(-z0));
        const float s1  = 1.f / (1.f + __expf(-z1));
        const float a2  = z0 * s0 * s1;
        const float a3  = sqrtf(z0 * z0 + z1 * z1 + 1e-12f);
        const float a4  = fmaxf(fabsf(z0), fabsf(z1));
        const float a5  = mx + log1pf(__expf(-fabsf(z0 - z1)));

        const float* w = wsm + p * Fdim;
        outv[p] = w[0] * mx + w[1] * a1 + w[2] * a2 + w[3] * a3 + w[4] * a4 + w[5] * a5;
    }
#pragma unroll
    for (int p = 0; p < Pdim; ++p)
        Hout[(size_t)b * DNEXT + p * CH + c] = outv[p];
}

// ---------------------------------------------------------------------------
// Output GEMM: Out[b, n] = sum_d H[b, d] * Wo[n, d] + bo[n]
// ---------------------------------------------------------------------------
__global__ __launch_bounds__(256) void gemm_out(
    const float* __restrict__ H,   // (B, 8192)
    const float* __restrict__ Wo,  // (NOUT, 8192)
    const float* __restrict__ bo,  // (NOUT)
    float* __restrict__ Out)       // (B, NOUT)
{
    const int n0 = blockIdx.x * BN;
    const int b0 = blockIdx.y * BM;

    __shared__ float As[BK][BM + 4];
    __shared__ float Bs[BK][BN + 4];

    const int tid = threadIdx.x;
    const int tx = tid & 15;
    const int ty = tid >> 4;

    float acc[4][4] = {};

    for (int k0 = 0; k0 < DNEXT; k0 += BK) {
#pragma unroll
        for (int q = 0; q < 4; ++q) {
            int idx = tid + q * 256;
            int c = idx & (BK - 1);
            int r = idx >> 4;
            As[c][r] = H[(size_t)(b0 + r) * DNEXT + (k0 + c)];
        }
#pragma unroll
        for (int q = 0; q < 4; ++q) {
            int idx = tid + q * 256;
            int c = idx & (BK - 1);
            int r = idx >> 4;
            int n = n0 + r;
            Bs[c][r] = (n < NOUT) ? Wo[(size_t)n * DNEXT + (k0 + c)] : 0.f;
        }
        __syncthreads();
#pragma unroll
        for (int c = 0; c < BK; ++c) {
            const float4 a4 = *reinterpret_cast<const float4*>(&As[c][ty * 4]);
            const float4 b4 = *reinterpret_cast<const float4*>(&Bs[c][tx * 4]);
            acc[0][0] += a4.x * b4.x; acc[0][1] += a4.x * b4.y; acc[0][2] += a4.x * b4.z; acc[0][3] += a4.x * b4.w;
            acc[1][0] += a4.y * b4.x; acc[1][1] += a4.y * b4.y; acc[1][2] += a4.y * b4.z; acc[1][3] += a4.y * b4.w;
            acc[2][0] += a4.z * b4.x; acc[2][1] += a4.z * b4.y; acc[2][2] += a4.z * b4.z; acc[2][3] += a4.z * b4.w;
            acc[3][0] += a4.w * b4.x; acc[3][1] += a4.w * b4.y; acc[3][2] += a4.w * b4.z; acc[3][3] += a4.w * b4.w;
        }
        __syncthreads();
    }

#pragma unroll
    for (int i = 0; i < 4; ++i) {
        const int bb = b0 + ty * 4 + i;
#pragma unroll
        for (int j = 0; j < 4; ++j) {
            const int n = n0 + tx * 4 + j;
            if (n < NOUT)
                Out[(size_t)bb * NOUT + n] = acc[i][j] + bo[n];
        }
    }
}

// ---------------------------------------------------------------------------
extern "C" void kernel_launch(void* const* d_in, const int* in_sizes, int n_in,
                              void* d_out, int out_size, void* d_ws, size_t ws_size,
                              hipStream_t stream)
{
    const float* x     = (const float*)d_in[0];
    const int*   perms = (const int*)  d_in[1];
    const float* W     = (const float*)d_in[2];
    const float* bvec  = (const float*)d_in[3];
    const float* gamma = (const float*)d_in[4];
    const float* beta  = (const float*)d_in[5];
    const float* alpha = (const float*)d_in[6];
    const float* Wo    = (const float*)d_in[7];
    const float* bo    = (const float*)d_in[8];
    float* out = (float*)d_out;

    float* ws = (float*)d_ws;
    float* h      = ws;                              // B * 8192
    float* y      = h + (size_t)Bdim * DNEXT;        // B * M
    float* psum   = y + (size_t)Bdim * Mdim;         // NRCHUNK * M
    float* psumsq = psum + (size_t)NRCHUNK * Mdim;   // NRCHUNK * M
    float* scale  = psumsq + (size_t)NRCHUNK * Mdim; // M
    float* shift  = scale + Mdim;                    // M
    float* wsm    = shift + Mdim;                    // L*P*F

    alpha_softmax<<<1, 64, 0, stream>>>(alpha, wsm);

    const float* hin = x;
    for (int l = 0; l < Lnum; ++l) {
        dim3 gg(MG / BN, Bdim / BM, Gdim);
        gemm_grouped<<<gg, 256, 0, stream>>>(
            hin, W + (size_t)l * Gdim * MG * CIN, bvec + (size_t)l * Gdim * MG, y);

        dim3 gs(Mdim / 256, NRCHUNK);
        bn_stats<<<gs, 256, 0, stream>>>(y, psum, psumsq);
        bn_finalize<<<Mdim / 256, 256, 0, stream>>>(
            psum, psumsq, gamma + (size_t)l * Mdim, beta + (size_t)l * Mdim, scale, shift);

        dim3 gc(CH / 256, Bdim);
        combinact_kernel<<<gc, 256, 0, stream>>>(
            y, scale, shift, perms + (size_t)l * Pdim * Mdim, wsm + l * Pdim * Fdim, h);

        hin = h;
    }

    dim3 go((NOUT + BN - 1) / BN, Bdim / BM);
    gemm_out<<<go, 256, 0, stream>>>(h, Wo, bo, out);
}

// Round 2
// 911.332 us; speedup vs baseline: 3.4111x; 3.4111x over previous
//
#include <hip/hip_runtime.h>
#include <math.h>

#define Lnum 3
#define Mdim 4096
#define Pdim 4
#define Gdim 4
#define NIN 8192
#define NOUT 1000
#define Bdim 2048
#define Fdim 6
#define CIN 2048      // input channels per group (all layers)
#define MG 1024       // M / G
#define CH 2048       // M / K
#define DNEXT 8192
#define RCHUNK 128
#define NRCHUNK (Bdim / RCHUNK)

typedef short bf16x8 __attribute__((ext_vector_type(8)));
typedef float f32x4 __attribute__((ext_vector_type(4)));

__device__ __forceinline__ short f2bf(float f) {
    union { float f; unsigned u; } v; v.f = f;
    unsigned u = v.u;
    unsigned r = (u + 0x7fffu + ((u >> 16) & 1u)) >> 16;
    return (short)r;
}

// ---------------------------------------------------------------------------
// f32 -> bf16 elementwise (n8 = count/8)
// ---------------------------------------------------------------------------
__global__ __launch_bounds__(256) void convert_f32_bf16(
    const float* __restrict__ src, short* __restrict__ dst, int n8)
{
    int i = blockIdx.x * 256 + threadIdx.x;
    if (i >= n8) return;
    const float4* s = (const float4*)src + (size_t)i * 2;
    float4 v0 = s[0], v1 = s[1];
    bf16x8 o;
    o[0] = f2bf(v0.x); o[1] = f2bf(v0.y); o[2] = f2bf(v0.z); o[3] = f2bf(v0.w);
    o[4] = f2bf(v1.x); o[5] = f2bf(v1.y); o[6] = f2bf(v1.z); o[7] = f2bf(v1.w);
    *((bf16x8*)dst + i) = o;
}

// Wo (1000 x 8192) f32 -> padded (1024 x 8192) bf16, pad rows zero
__global__ __launch_bounds__(256) void convert_wo(
    const float* __restrict__ src, short* __restrict__ dst)
{
    int i = blockIdx.x * 256 + threadIdx.x;   // one per 8 elements of dst
    int row = i >> 10;                         // 8192/8 = 1024 chunks per row
    bf16x8 o;
    if (row < NOUT) {
        const float4* s = (const float4*)(src + (size_t)row * DNEXT + (i & 1023) * 8);
        float4 v0 = s[0], v1 = s[1];
        o[0] = f2bf(v0.x); o[1] = f2bf(v0.y); o[2] = f2bf(v0.z); o[3] = f2bf(v0.w);
        o[4] = f2bf(v1.x); o[5] = f2bf(v1.y); o[6] = f2bf(v1.z); o[7] = f2bf(v1.w);
    } else {
        for (int j = 0; j < 8; ++j) o[j] = 0;
    }
    *((bf16x8*)dst + i) = o;
}

// x (B x 8192) f32 -> grouped bf16 planes hg[g][b][c] = x[b][4c+g]
__global__ __launch_bounds__(256) void x_to_grouped(
    const float* __restrict__ x, short* __restrict__ hg)
{
    const int c = blockIdx.x * 256 + threadIdx.x;   // 0..2047
    const int b = blockIdx.y;
    float4 v = *(const float4*)(x + (size_t)b * NIN + 4 * c);
    const size_t plane = (size_t)Bdim * CIN;
    hg[0 * plane + (size_t)b * CIN + c] = f2bf(v.x);
    hg[1 * plane + (size_t)b * CIN + c] = f2bf(v.y);
    hg[2 * plane + (size_t)b * CIN + c] = f2bf(v.z);
    hg[3 * plane + (size_t)b * CIN + c] = f2bf(v.w);
}

// ---------------------------------------------------------------------------
// MFMA bf16 GEMM: C[row, n] = sum_k A[row,k]*B[n,k] + bias[n]
// A: (rows x K) bf16 row-major; B: (N x K) bf16 row-major.
// Block tile 128 x BN_T, BK=32, 4 waves (2x2), frag 4 x (BN_T/32) per wave.
// C store: C[row*ldc + n*cstride] for n < nbound. blockIdx.z selects group
// via aZ/bZ/biasZ/cZ element strides.
// ---------------------------------------------------------------------------
template<int BN_T>
__global__ __launch_bounds__(256) void gemm_mfma(
    const short* __restrict__ A0, size_t aZ,
    const short* __restrict__ B0, size_t bZ,
    const float* __restrict__ bias0, size_t biasZ,
    float* __restrict__ C0, size_t cZ,
    int K, int ldc, int cstride, int nbound)
{
    constexpr int FN = BN_T / 32;
    const int g = blockIdx.z;
    const short* A  = A0 + aZ * g;
    const short* Bm = B0 + bZ * g;
    const float* bias = bias0 + biasZ * g;
    float* C = C0 + cZ * g;

    const int n0 = blockIdx.x * BN_T;
    const int b0 = blockIdx.y * 128;

    __shared__ short As[128 * 32];
    __shared__ short Bs[BN_T * 32];

    const int tid  = threadIdx.x;
    const int w    = tid >> 6;
    const int lane = tid & 63;
    const int wr = w >> 1, wc = w & 1;

    f32x4 acc[4][FN];
#pragma unroll
    for (int m = 0; m < 4; ++m)
#pragma unroll
        for (int n = 0; n < FN; ++n) acc[m][n] = (f32x4)0.f;

    const int arow = lane >> 2;          // row within 16-row segment
    const int acol = (lane & 3) * 8;     // k offset within 32

    for (int k0 = 0; k0 < K; k0 += 32) {
#pragma unroll
        for (int s = w; s < 8; s += 4) {
            const short* ga = A + (size_t)(b0 + s * 16 + arow) * K + k0 + acol;
            __builtin_amdgcn_global_load_lds(
                (const __attribute__((address_space(1))) void*)ga,
                (__attribute__((address_space(3))) void*)(As + s * 512), 16, 0, 0);
        }
#pragma unroll
        for (int s = w; s < BN_T / 16; s += 4) {
            const short* gb = Bm + (size_t)(n0 + s * 16 + arow) * K + k0 + acol;
            __builtin_amdgcn_global_load_lds(
                (const __attribute__((address_space(1))) void*)gb,
                (__attribute__((address_space(3))) void*)(Bs + s * 512), 16, 0, 0);
        }
        __syncthreads();

        bf16x8 af[4], bff[FN];
#pragma unroll
        for (int m = 0; m < 4; ++m)
            af[m] = *(const bf16x8*)(As + (wr * 64 + m * 16 + (lane & 15)) * 32 + (lane >> 4) * 8);
#pragma unroll
        for (int n = 0; n < FN; ++n)
            bff[n] = *(const bf16x8*)(Bs + (wc * (BN_T / 2) + n * 16 + (lane & 15)) * 32 + (lane >> 4) * 8);
#pragma unroll
        for (int m = 0; m < 4; ++m)
#pragma unroll
            for (int n = 0; n < FN; ++n)
                acc[m][n] = __builtin_amdgcn_mfma_f32_16x16x32_bf16(af[m], bff[n], acc[m][n], 0, 0, 0);
        __syncthreads();
    }

    const int fr = lane & 15, fq = lane >> 4;
#pragma unroll
    for (int m = 0; m < 4; ++m) {
#pragma unroll
        for (int n = 0; n < FN; ++n) {
#pragma unroll
            for (int j = 0; j < 4; ++j) {
                const int row = b0 + wr * 64 + m * 16 + fq * 4 + j;
                const int col = n0 + wc * (BN_T / 2) + n * 16 + fr;
                if (col < nbound)
                    C[(size_t)row * ldc + (size_t)col * cstride] = acc[m][n][j] + bias[col];
            }
        }
    }
}

// ---------------------------------------------------------------------------
// BatchNorm stats, deterministic two stage (Y is f32 B x M)
// ---------------------------------------------------------------------------
__global__ __launch_bounds__(256) void bn_stats(
    const float* __restrict__ Y, float* __restrict__ psum, float* __restrict__ psumsq)
{
    const int j  = blockIdx.x * 256 + threadIdx.x;
    const int r0 = blockIdx.y * RCHUNK;
    float s = 0.f, ss = 0.f;
    for (int r = 0; r < RCHUNK; ++r) {
        float v = Y[(size_t)(r0 + r) * Mdim + j];
        s += v; ss += v * v;
    }
    psum[blockIdx.y * Mdim + j]   = s;
    psumsq[blockIdx.y * Mdim + j] = ss;
}

__global__ __launch_bounds__(256) void bn_finalize(
    const float* __restrict__ psum, const float* __restrict__ psumsq,
    const float* __restrict__ gamma, const float* __restrict__ beta,
    float* __restrict__ scale, float* __restrict__ shift)
{
    const int j = blockIdx.x * 256 + threadIdx.x;
    if (j >= Mdim) return;
    float s = 0.f, ss = 0.f;
    for (int r = 0; r < NRCHUNK; ++r) {
        s  += psum[r * Mdim + j];
        ss += psumsq[r * Mdim + j];
    }
    const float mu  = s * (1.f / Bdim);
    const float var = ss * (1.f / Bdim) - mu * mu;
    const float sc  = gamma[j] * rsqrtf(var + 1e-5f);
    scale[j] = sc;
    shift[j] = beta[j] - mu * sc;
}

__global__ void alpha_softmax(const float* __restrict__ alpha, float* __restrict__ wsm)
{
    const int idx = threadIdx.x;
    if (idx >= Lnum * Pdim) return;
    const float* a = alpha + idx * Fdim;
    float mx = a[0];
#pragma unroll
    for (int f = 1; f < Fdim; ++f) mx = fmaxf(mx, a[f]);
    float e[Fdim]; float s = 0.f;
#pragma unroll
    for (int f = 0; f < Fdim; ++f) { e[f] = __expf(a[f] - mx); s += e[f]; }
    const float inv = 1.f / s;
#pragma unroll
    for (int f = 0; f < Fdim; ++f) wsm[idx * Fdim + f] = e[f] * inv;
}

// ---------------------------------------------------------------------------
// Fused normalize + permutation gather + combinact (K=2 closed form)
// MODE 0: write grouped bf16 planes hg[g][b][cin], g=c&3, cin=p*512+(c>>2)
// MODE 1: write flat bf16 h[b][p*CH + c]
// ---------------------------------------------------------------------------
template<int MODE>
__global__ __launch_bounds__(256) void combinact_kernel(
    const float* __restrict__ Y, const float* __restrict__ scale,
    const float* __restrict__ shift, const int* __restrict__ perm,
    const float* __restrict__ wsm, short* __restrict__ out)
{
    const int c = blockIdx.x * 256 + threadIdx.x;   // 0..CH-1
    const int b = blockIdx.y;
    const float* yr = Y + (size_t)b * Mdim;

#pragma unroll
    for (int p = 0; p < Pdim; ++p) {
        const int j0 = perm[p * Mdim + c * 2];
        const int j1 = perm[p * Mdim + c * 2 + 1];
        const float z0 = yr[j0] * scale[j0] + shift[j0];
        const float z1 = yr[j1] * scale[j1] + shift[j1];

        const float mx  = fmaxf(z0, z1);
        const float pr  = z0 * z1;
        const float sgn = (pr > 0.f) ? 1.f : ((pr < 0.f) ? -1.f : 0.f);
        const float a1  = sgn * sqrtf(fabsf(pr) + 1e-12f);
        const float s0  = 1.f / (1.f + __expf(-z0));
        const float s1  = 1.f / (1.f + __expf(-z1));
        const float a2  = z0 * s0 * s1;
        const float a3  = sqrtf(z0 * z0 + z1 * z1 + 1e-12f);
        const float a4  = fmaxf(fabsf(z0), fabsf(z1));
        const float a5  = mx + log1pf(__expf(-fabsf(z0 - z1)));

        const float* wv = wsm + p * Fdim;
        const float v = wv[0] * mx + wv[1] * a1 + wv[2] * a2 + wv[3] * a3 + wv[4] * a4 + wv[5] * a5;

        if (MODE == 0)
            out[(size_t)(c & 3) * ((size_t)Bdim * CIN) + (size_t)b * CIN + p * 512 + (c >> 2)] = f2bf(v);
        else
            out[(size_t)b * DNEXT + p * CH + c] = f2bf(v);
    }
}

// ---------------------------------------------------------------------------
extern "C" void kernel_launch(void* const* d_in, const int* in_sizes, int n_in,
                              void* d_out, int out_size, void* d_ws, size_t ws_size,
                              hipStream_t stream)
{
    const float* x     = (const float*)d_in[0];
    const int*   perms = (const int*)  d_in[1];
    const float* W     = (const float*)d_in[2];
    const float* bvec  = (const float*)d_in[3];
    const float* gamma = (const float*)d_in[4];
    const float* beta  = (const float*)d_in[5];
    const float* alpha = (const float*)d_in[6];
    const float* Wo    = (const float*)d_in[7];
    const float* bo    = (const float*)d_in[8];
    float* out = (float*)d_out;

    char* ws = (char*)d_ws;
    float* y      = (float*)ws;                             // B*M f32
    short* hg     = (short*)(y + (size_t)Bdim * Mdim);      // G*B*CIN bf16
    short* hflat  = hg + (size_t)Gdim * Bdim * CIN;         // B*8192 bf16
    short* Wlb    = hflat + (size_t)Bdim * DNEXT;           // G*MG*CIN bf16
    short* Wob    = Wlb + (size_t)Gdim * MG * CIN;          // 1024*8192 bf16
    float* psum   = (float*)(Wob + (size_t)1024 * DNEXT);   // NRCHUNK*M
    float* psumsq = psum + (size_t)NRCHUNK * Mdim;
    float* scale  = psumsq + (size_t)NRCHUNK * Mdim;
    float* shift  = scale + Mdim;
    float* wsm    = shift + Mdim;

    alpha_softmax<<<1, 64, 0, stream>>>(alpha, wsm);
    convert_wo<<<(1024 * 1024) / 256, 256, 0, stream>>>(Wo, Wob);
    x_to_grouped<<<dim3(CIN / 256, Bdim), 256, 0, stream>>>(x, hg);

    const size_t planeA = (size_t)Bdim * CIN;    // hg group stride
    const size_t planeB = (size_t)MG * CIN;      // W group stride

    for (int l = 0; l < Lnum; ++l) {
        convert_f32_bf16<<<(Gdim * MG * CIN / 8) / 256, 256, 0, stream>>>(
            W + (size_t)l * Gdim * MG * CIN, Wlb, Gdim * MG * CIN / 8);

        dim3 gg(MG / 128, Bdim / 128, Gdim);
        gemm_mfma<128><<<gg, 256, 0, stream>>>(
            hg, planeA, Wlb, planeB,
            bvec + (size_t)l * Gdim * MG, (size_t)MG,
            y, (size_t)1,
            CIN, Mdim, Gdim, MG);

        dim3 gs(Mdim / 256, NRCHUNK);
        bn_stats<<<gs, 256, 0, stream>>>(y, psum, psumsq);
        bn_finalize<<<Mdim / 256, 256, 0, stream>>>(
            psum, psumsq, gamma + (size_t)l * Mdim, beta + (size_t)l * Mdim, scale, shift);

        dim3 gc(CH / 256, Bdim);
        if (l < Lnum - 1)
            combinact_kernel<0><<<gc, 256, 0, stream>>>(
                y, scale, shift, perms + (size_t)l * Pdim * Mdim, wsm + l * Pdim * Fdim, hg);
        else
            combinact_kernel<1><<<gc, 256, 0, stream>>>(
                y, scale, shift, perms + (size_t)l * Pdim * Mdim, wsm + l * Pdim * Fdim, hflat);

        (void)planeA;
    }

    dim3 go(1024 / 64, Bdim / 128, 1);
    gemm_mfma<64><<<go, 256, 0, stream>>>(
        hflat, 0, Wob, 0, bo, 0, out, 0,
        DNEXT, NOUT, 1, NOUT);
}

// Round 3
// 636.555 us; speedup vs baseline: 4.8835x; 1.4317x over previous
//
#include <hip/hip_runtime.h>
#include <math.h>

#define Lnum 3
#define Mdim 4096
#define Pdim 4
#define Gdim 4
#define NIN 8192
#define NOUT 1000
#define Bdim 2048
#define Fdim 6
#define CIN 2048      // input channels per group (all layers)
#define MG 1024       // M / G
#define CH 2048       // M / K
#define DNEXT 8192
#define RCHUNK 128
#define NRCHUNK (Bdim / RCHUNK)

typedef short bf16x8 __attribute__((ext_vector_type(8)));
typedef float f32x4 __attribute__((ext_vector_type(4)));

__device__ __forceinline__ short f2bf(float f) {
    union { float f; unsigned u; } v; v.f = f;
    unsigned u = v.u;
    unsigned r = (u + 0x7fffu + ((u >> 16) & 1u)) >> 16;
    return (short)r;
}

// ---------------------------------------------------------------------------
// f32 -> bf16 elementwise (n8 = count/8)
// ---------------------------------------------------------------------------
__global__ __launch_bounds__(256) void convert_f32_bf16(
    const float* __restrict__ src, short* __restrict__ dst, int n8)
{
    int i = blockIdx.x * 256 + threadIdx.x;
    if (i >= n8) return;
    const float4* s = (const float4*)src + (size_t)i * 2;
    float4 v0 = s[0], v1 = s[1];
    bf16x8 o;
    o[0] = f2bf(v0.x); o[1] = f2bf(v0.y); o[2] = f2bf(v0.z); o[3] = f2bf(v0.w);
    o[4] = f2bf(v1.x); o[5] = f2bf(v1.y); o[6] = f2bf(v1.z); o[7] = f2bf(v1.w);
    *((bf16x8*)dst + i) = o;
}

// Wo (1000 x 8192) f32 -> padded (1024 x 8192) bf16, pad rows zero
__global__ __launch_bounds__(256) void convert_wo(
    const float* __restrict__ src, short* __restrict__ dst)
{
    int i = blockIdx.x * 256 + threadIdx.x;
    int row = i >> 10;
    bf16x8 o;
    if (row < NOUT) {
        const float4* s = (const float4*)(src + (size_t)row * DNEXT + (i & 1023) * 8);
        float4 v0 = s[0], v1 = s[1];
        o[0] = f2bf(v0.x); o[1] = f2bf(v0.y); o[2] = f2bf(v0.z); o[3] = f2bf(v0.w);
        o[4] = f2bf(v1.x); o[5] = f2bf(v1.y); o[6] = f2bf(v1.z); o[7] = f2bf(v1.w);
    } else {
        for (int j = 0; j < 8; ++j) o[j] = 0;
    }
    *((bf16x8*)dst + i) = o;
}

// x (B x 8192) f32 -> grouped bf16 planes hg[g][b][c] = x[b][4c+g]
__global__ __launch_bounds__(256) void x_to_grouped(
    const float* __restrict__ x, short* __restrict__ hg)
{
    const int c = blockIdx.x * 256 + threadIdx.x;
    const int b = blockIdx.y;
    float4 v = *(const float4*)(x + (size_t)b * NIN + 4 * c);
    const size_t plane = (size_t)Bdim * CIN;
    hg[0 * plane + (size_t)b * CIN + c] = f2bf(v.x);
    hg[1 * plane + (size_t)b * CIN + c] = f2bf(v.y);
    hg[2 * plane + (size_t)b * CIN + c] = f2bf(v.z);
    hg[3 * plane + (size_t)b * CIN + c] = f2bf(v.w);
}

// ---------------------------------------------------------------------------
// MFMA bf16 GEMM: C[row, n] = sum_k A[row,k]*B[n,k] (+ bias[n] if bias!=null)
// Block tile 128 x BN_T, BK=32, 4 waves (2x2). blockIdx.z advances A/B/C by
// aZ/bZ/cZ elements (group or K-split plane).
// ---------------------------------------------------------------------------
template<int BN_T>
__global__ __launch_bounds__(256) void gemm_mfma(
    const short* __restrict__ A0, size_t aZ, int lda,
    const short* __restrict__ B0, size_t bZ, int ldb,
    const float* __restrict__ bias0, size_t biasZ,
    float* __restrict__ C0, size_t cZ,
    int K, int ldc, int cstride, int nbound)
{
    constexpr int FN = BN_T / 32;
    const int g = blockIdx.z;
    const short* A  = A0 + aZ * g;
    const short* Bm = B0 + bZ * g;
    float* C = C0 + cZ * g;

    const int n0 = blockIdx.x * BN_T;
    const int b0 = blockIdx.y * 128;

    __shared__ short As[128 * 32];
    __shared__ short Bs[BN_T * 32];

    const int tid  = threadIdx.x;
    const int w    = tid >> 6;
    const int lane = tid & 63;
    const int wr = w >> 1, wc = w & 1;

    f32x4 acc[4][FN];
#pragma unroll
    for (int m = 0; m < 4; ++m)
#pragma unroll
        for (int n = 0; n < FN; ++n) acc[m][n] = (f32x4)0.f;

    const int arow = lane >> 2;
    const int acol = (lane & 3) * 8;

    for (int k0 = 0; k0 < K; k0 += 32) {
#pragma unroll
        for (int s = w; s < 8; s += 4) {
            const short* ga = A + (size_t)(b0 + s * 16 + arow) * lda + k0 + acol;
            __builtin_amdgcn_global_load_lds(
                (const __attribute__((address_space(1))) void*)ga,
                (__attribute__((address_space(3))) void*)(As + s * 512), 16, 0, 0);
        }
#pragma unroll
        for (int s = w; s < BN_T / 16; s += 4) {
            const short* gb = Bm + (size_t)(n0 + s * 16 + arow) * ldb + k0 + acol;
            __builtin_amdgcn_global_load_lds(
                (const __attribute__((address_space(1))) void*)gb,
                (__attribute__((address_space(3))) void*)(Bs + s * 512), 16, 0, 0);
        }
        __syncthreads();

        bf16x8 af[4], bff[FN];
#pragma unroll
        for (int m = 0; m < 4; ++m)
            af[m] = *(const bf16x8*)(As + (wr * 64 + m * 16 + (lane & 15)) * 32 + (lane >> 4) * 8);
#pragma unroll
        for (int n = 0; n < FN; ++n)
            bff[n] = *(const bf16x8*)(Bs + (wc * (BN_T / 2) + n * 16 + (lane & 15)) * 32 + (lane >> 4) * 8);
#pragma unroll
        for (int m = 0; m < 4; ++m)
#pragma unroll
            for (int n = 0; n < FN; ++n)
                acc[m][n] = __builtin_amdgcn_mfma_f32_16x16x32_bf16(af[m], bff[n], acc[m][n], 0, 0, 0);
        __syncthreads();
    }

    const int fr = lane & 15, fq = lane >> 4;
#pragma unroll
    for (int m = 0; m < 4; ++m) {
#pragma unroll
        for (int n = 0; n < FN; ++n) {
#pragma unroll
            for (int j = 0; j < 4; ++j) {
                const int row = b0 + wr * 64 + m * 16 + fq * 4 + j;
                const int col = n0 + wc * (BN_T / 2) + n * 16 + fr;
                if (col < nbound) {
                    float v = acc[m][n][j];
                    if (bias0) v += bias0[biasZ * g + col];
                    C[(size_t)row * ldc + (size_t)col * cstride] = v;
                }
            }
        }
    }
}

// out[b,n] = p0[b,n] + p1[b,n] + bo[n]
__global__ __launch_bounds__(256) void reduce_out(
    const float* __restrict__ p0, const float* __restrict__ p1,
    const float* __restrict__ bo, float* __restrict__ out)
{
    const int n = blockIdx.x * 256 + threadIdx.x;
    const int b = blockIdx.y;
    if (n >= NOUT) return;
    out[(size_t)b * NOUT + n] = p0[(size_t)b * 1024 + n] + p1[(size_t)b * 1024 + n] + bo[n];
}

// ---------------------------------------------------------------------------
// BatchNorm stats, deterministic two stage
// ---------------------------------------------------------------------------
__global__ __launch_bounds__(256) void bn_stats(
    const float* __restrict__ Y, float* __restrict__ psum, float* __restrict__ psumsq)
{
    const int j  = blockIdx.x * 256 + threadIdx.x;
    const int r0 = blockIdx.y * RCHUNK;
    float s = 0.f, ss = 0.f;
    for (int r = 0; r < RCHUNK; ++r) {
        float v = Y[(size_t)(r0 + r) * Mdim + j];
        s += v; ss += v * v;
    }
    psum[blockIdx.y * Mdim + j]   = s;
    psumsq[blockIdx.y * Mdim + j] = ss;
}

__global__ __launch_bounds__(256) void bn_finalize(
    const float* __restrict__ psum, const float* __restrict__ psumsq,
    const float* __restrict__ gamma, const float* __restrict__ beta,
    float* __restrict__ scale, float* __restrict__ shift)
{
    const int j = blockIdx.x * 256 + threadIdx.x;
    if (j >= Mdim) return;
    float s = 0.f, ss = 0.f;
    for (int r = 0; r < NRCHUNK; ++r) {
        s  += psum[r * Mdim + j];
        ss += psumsq[r * Mdim + j];
    }
    const float mu  = s * (1.f / Bdim);
    const float var = ss * (1.f / Bdim) - mu * mu;
    const float sc  = gamma[j] * rsqrtf(var + 1e-5f);
    scale[j] = sc;
    shift[j] = beta[j] - mu * sc;
}

__global__ void alpha_softmax(const float* __restrict__ alpha, float* __restrict__ wsm)
{
    const int idx = threadIdx.x;
    if (idx >= Lnum * Pdim) return;
    const float* a = alpha + idx * Fdim;
    float mx = a[0];
#pragma unroll
    for (int f = 1; f < Fdim; ++f) mx = fmaxf(mx, a[f]);
    float e[Fdim]; float s = 0.f;
#pragma unroll
    for (int f = 0; f < Fdim; ++f) { e[f] = __expf(a[f] - mx); s += e[f]; }
    const float inv = 1.f / s;
#pragma unroll
    for (int f = 0; f < Fdim; ++f) wsm[idx * Fdim + f] = e[f] * inv;
}

// ---------------------------------------------------------------------------
// Fused normalize + permutation gather + combinact (K=2 closed form).
// One block per batch row; normalized row staged in LDS; gathers hit LDS.
// MODE 0: out grouped planes hg[g][b][p*512+q], thread handles (g, q), c=q*4+g
// MODE 1: out flat h[b][p*CH+c]
// ---------------------------------------------------------------------------
template<int MODE>
__global__ __launch_bounds__(256) void combinact_kernel(
    const float* __restrict__ Y, const float* __restrict__ scale,
    const float* __restrict__ shift, const int* __restrict__ perm,
    const float* __restrict__ wsm, short* __restrict__ out)
{
    __shared__ float yn[Mdim];
    const int b   = blockIdx.x;
    const int tid = threadIdx.x;

#pragma unroll
    for (int k = 0; k < 4; ++k) {
        const int i4 = k * 256 + tid;
        const float4 v  = *(const float4*)(Y + (size_t)b * Mdim + (size_t)i4 * 4);
        const float4 sc = *(const float4*)(scale + i4 * 4);
        const float4 sh = *(const float4*)(shift + i4 * 4);
        float4 r;
        r.x = v.x * sc.x + sh.x;
        r.y = v.y * sc.y + sh.y;
        r.z = v.z * sc.z + sh.z;
        r.w = v.w * sc.w + sh.w;
        *(float4*)(yn + i4 * 4) = r;
    }
    __syncthreads();

    float wv[Pdim][Fdim];
#pragma unroll
    for (int p = 0; p < Pdim; ++p)
#pragma unroll
        for (int f = 0; f < Fdim; ++f) wv[p][f] = wsm[p * Fdim + f];

#pragma unroll
    for (int k = 0; k < 8; ++k) {
        const int idx = k * 256 + tid;
        int c, g = 0, q = 0;
        if (MODE == 0) { g = idx >> 9; q = idx & 511; c = q * 4 + g; }
        else           { c = idx; }

#pragma unroll
        for (int p = 0; p < Pdim; ++p) {
            const int2 jj = *(const int2*)(perm + p * Mdim + 2 * c);
            const float z0 = yn[jj.x];
            const float z1 = yn[jj.y];

            const float mx  = fmaxf(z0, z1);
            const float pr  = z0 * z1;
            const float sgn = (pr > 0.f) ? 1.f : ((pr < 0.f) ? -1.f : 0.f);
            const float a1  = sgn * sqrtf(fabsf(pr) + 1e-12f);
            const float s0  = 1.f / (1.f + __expf(-z0));
            const float s1  = 1.f / (1.f + __expf(-z1));
            const float a2  = z0 * s0 * s1;
            const float a3  = sqrtf(z0 * z0 + z1 * z1 + 1e-12f);
            const float a4  = fmaxf(fabsf(z0), fabsf(z1));
            const float a5  = mx + log1pf(__expf(-fabsf(z0 - z1)));

            const float v = wv[p][0] * mx + wv[p][1] * a1 + wv[p][2] * a2 +
                            wv[p][3] * a3 + wv[p][4] * a4 + wv[p][5] * a5;

            if (MODE == 0)
                out[(size_t)g * ((size_t)Bdim * CIN) + (size_t)b * CIN + p * 512 + q] = f2bf(v);
            else
                out[(size_t)b * DNEXT + p * CH + c] = f2bf(v);
        }
    }
}

// ---------------------------------------------------------------------------
extern "C" void kernel_launch(void* const* d_in, const int* in_sizes, int n_in,
                              void* d_out, int out_size, void* d_ws, size_t ws_size,
                              hipStream_t stream)
{
    const float* x     = (const float*)d_in[0];
    const int*   perms = (const int*)  d_in[1];
    const float* W     = (const float*)d_in[2];
    const float* bvec  = (const float*)d_in[3];
    const float* gamma = (const float*)d_in[4];
    const float* beta  = (const float*)d_in[5];
    const float* alpha = (const float*)d_in[6];
    const float* Wo    = (const float*)d_in[7];
    const float* bo    = (const float*)d_in[8];
    float* out = (float*)d_out;

    char* ws = (char*)d_ws;
    float* y      = (float*)ws;                             // B*M f32
    short* hg     = (short*)(y + (size_t)Bdim * Mdim);      // G*B*CIN bf16
    short* hflat  = hg + (size_t)Gdim * Bdim * CIN;         // B*8192 bf16
    short* Wlb    = hflat + (size_t)Bdim * DNEXT;           // G*MG*CIN bf16 (aliased by out partials later)
    short* Wob    = Wlb + (size_t)Gdim * MG * CIN;          // 1024*8192 bf16
    float* psum   = (float*)(Wob + (size_t)1024 * DNEXT);
    float* psumsq = psum + (size_t)NRCHUNK * Mdim;
    float* scale  = psumsq + (size_t)NRCHUNK * Mdim;
    float* shift  = scale + Mdim;
    float* wsm    = shift + Mdim;

    float* part = (float*)Wlb;   // 2 x (B*1024) f32 = 16 MB, fits in Wlb's 32 MB

    alpha_softmax<<<1, 64, 0, stream>>>(alpha, wsm);
    convert_wo<<<(1024 * 1024) / 256, 256, 0, stream>>>(Wo, Wob);
    x_to_grouped<<<dim3(CIN / 256, Bdim), 256, 0, stream>>>(x, hg);

    const size_t planeA = (size_t)Bdim * CIN;
    const size_t planeB = (size_t)MG * CIN;

    for (int l = 0; l < Lnum; ++l) {
        convert_f32_bf16<<<(Gdim * MG * CIN / 8) / 256, 256, 0, stream>>>(
            W + (size_t)l * Gdim * MG * CIN, Wlb, Gdim * MG * CIN / 8);

        dim3 gg(MG / 128, Bdim / 128, Gdim);
        gemm_mfma<128><<<gg, 256, 0, stream>>>(
            hg, planeA, CIN, Wlb, planeB, CIN,
            bvec + (size_t)l * Gdim * MG, (size_t)MG,
            y, (size_t)1,
            CIN, Mdim, Gdim, MG);

        dim3 gs(Mdim / 256, NRCHUNK);
        bn_stats<<<gs, 256, 0, stream>>>(y, psum, psumsq);
        bn_finalize<<<Mdim / 256, 256, 0, stream>>>(
            psum, psumsq, gamma + (size_t)l * Mdim, beta + (size_t)l * Mdim, scale, shift);

        if (l < Lnum - 1)
            combinact_kernel<0><<<Bdim, 256, 0, stream>>>(
                y, scale, shift, perms + (size_t)l * Pdim * Mdim, wsm + l * Pdim * Fdim, hg);
        else
            combinact_kernel<1><<<Bdim, 256, 0, stream>>>(
                y, scale, shift, perms + (size_t)l * Pdim * Mdim, wsm + l * Pdim * Fdim, hflat);
    }

    // Output GEMM, split-K=2 (2 blocks/CU), partials then deterministic reduce.
    dim3 go(1024 / 64, Bdim / 128, 2);
    gemm_mfma<64><<<go, 256, 0, stream>>>(
        hflat, (size_t)4096, DNEXT, Wob, (size_t)4096, DNEXT,
        nullptr, 0,
        part, (size_t)Bdim * 1024,
        4096, 1024, 1, 1024);

    dim3 gr(4, Bdim);
    reduce_out<<<gr, 256, 0, stream>>>(part, part + (size_t)Bdim * 1024, bo, out);
}

// Round 4
// 595.548 us; speedup vs baseline: 5.2198x; 1.0689x over previous
//
#include <hip/hip_runtime.h>
#include <math.h>

#define Lnum 3
#define Mdim 4096
#define Pdim 4
#define Gdim 4
#define NIN 8192
#define NOUT 1000
#define Bdim 2048
#define Fdim 6
#define CIN 2048      // input channels per group (all layers)
#define MG 1024       // M / G
#define CH 2048       // M / K
#define DNEXT 8192
#define RCHUNK 128
#define NRCHUNK (Bdim / RCHUNK)

typedef short bf16x8 __attribute__((ext_vector_type(8)));
typedef float f32x4 __attribute__((ext_vector_type(4)));

__device__ __forceinline__ short f2bf(float f) {
    union { float f; unsigned u; } v; v.f = f;
    unsigned u = v.u;
    unsigned r = (u + 0x7fffu + ((u >> 16) & 1u)) >> 16;
    return (short)r;
}

// ---------------------------------------------------------------------------
__global__ __launch_bounds__(256) void convert_f32_bf16(
    const float* __restrict__ src, short* __restrict__ dst, int n8)
{
    int i = blockIdx.x * 256 + threadIdx.x;
    if (i >= n8) return;
    const float4* s = (const float4*)src + (size_t)i * 2;
    float4 v0 = s[0], v1 = s[1];
    bf16x8 o;
    o[0] = f2bf(v0.x); o[1] = f2bf(v0.y); o[2] = f2bf(v0.z); o[3] = f2bf(v0.w);
    o[4] = f2bf(v1.x); o[5] = f2bf(v1.y); o[6] = f2bf(v1.z); o[7] = f2bf(v1.w);
    *((bf16x8*)dst + i) = o;
}

// Wo (1000 x 8192) f32 -> padded (1024 x 8192) bf16, pad rows zero
__global__ __launch_bounds__(256) void convert_wo(
    const float* __restrict__ src, short* __restrict__ dst)
{
    int i = blockIdx.x * 256 + threadIdx.x;
    int row = i >> 10;
    bf16x8 o;
    if (row < NOUT) {
        const float4* s = (const float4*)(src + (size_t)row * DNEXT + (i & 1023) * 8);
        float4 v0 = s[0], v1 = s[1];
        o[0] = f2bf(v0.x); o[1] = f2bf(v0.y); o[2] = f2bf(v0.z); o[3] = f2bf(v0.w);
        o[4] = f2bf(v1.x); o[5] = f2bf(v1.y); o[6] = f2bf(v1.z); o[7] = f2bf(v1.w);
    } else {
        for (int j = 0; j < 8; ++j) o[j] = 0;
    }
    *((bf16x8*)dst + i) = o;
}

// x (B x 8192) f32 -> grouped bf16 planes hg[g][b][c] = x[b][4c+g]
__global__ __launch_bounds__(256) void x_to_grouped(
    const float* __restrict__ x, short* __restrict__ hg)
{
    const int c = blockIdx.x * 256 + threadIdx.x;
    const int b = blockIdx.y;
    float4 v = *(const float4*)(x + (size_t)b * NIN + 4 * c);
    const size_t plane = (size_t)Bdim * CIN;
    hg[0 * plane + (size_t)b * CIN + c] = f2bf(v.x);
    hg[1 * plane + (size_t)b * CIN + c] = f2bf(v.y);
    hg[2 * plane + (size_t)b * CIN + c] = f2bf(v.z);
    hg[3 * plane + (size_t)b * CIN + c] = f2bf(v.w);
}

// ---------------------------------------------------------------------------
// MFMA bf16 GEMM, double-buffered prefetch, BK=64, XOR-swizzled LDS.
// C[row, n] = sum_k A[row,k]*B[n,k] (+bias[n]); blockIdx.z -> aZ/bZ/cZ strides.
// Tile 128 x BN_T, 4 waves (2x2). K % 64 == 0. grid total % 8 == 0.
// ---------------------------------------------------------------------------
template<int BN_T>
__global__ __launch_bounds__(256) void gemm_mfma(
    const short* __restrict__ A0, size_t aZ, int lda,
    const short* __restrict__ B0, size_t bZ, int ldb,
    const float* __restrict__ bias0, size_t biasZ,
    float* __restrict__ C0, size_t cZ,
    int K, int ldc, int cstride, int nbound)
{
    constexpr int FN = BN_T / 32;

    // XCD-aware swizzle: consecutive same-XCD blocks take consecutive tiles.
    const int nx = gridDim.x, ny = gridDim.y;
    const int nwg = nx * ny * gridDim.z;
    const int lin = blockIdx.x + nx * (blockIdx.y + ny * blockIdx.z);
    int swz = (lin & 7) * (nwg >> 3) + (lin >> 3);
    const int bx = swz % nx; swz /= nx;
    const int by = swz % ny;
    const int g  = swz / ny;

    const short* A  = A0 + aZ * g;
    const short* Bm = B0 + bZ * g;
    float* C = C0 + cZ * g;

    const int n0 = bx * BN_T;
    const int b0 = by * 128;

    __shared__ short As[2][128 * 64];
    __shared__ short Bs[2][BN_T * 64];

    const int tid  = threadIdx.x;
    const int w    = tid >> 6;
    const int lane = tid & 63;
    const int wr = w >> 1, wc = w & 1;

    f32x4 acc[4][FN];
#pragma unroll
    for (int m = 0; m < 4; ++m)
#pragma unroll
        for (int n = 0; n < FN; ++n) acc[m][n] = (f32x4)0.f;

    const int srow  = lane >> 3;   // row within 8-row stage chunk
    const int sslot = lane & 7;    // 16B slot within 128B row

    // Stage one K-tile (k0..k0+64) into buffer `buf`. LDS dest is linear;
    // the global source slot is XOR-swizzled so that a swizzled ds_read
    // recovers linear data (both sides same involution).
    auto stage = [&](int buf, int k0) {
#pragma unroll
        for (int s = w; s < 16; s += 4) {
            const int r  = s * 8 + srow;
            const int gs = sslot ^ (r & 7);
            const short* ga = A + (size_t)(b0 + r) * lda + k0 + gs * 8;
            __builtin_amdgcn_global_load_lds(
                (const __attribute__((address_space(1))) void*)ga,
                (__attribute__((address_space(3))) void*)(&As[buf][s * 512]), 16, 0, 0);
        }
#pragma unroll
        for (int s = w; s < BN_T / 8; s += 4) {
            const int r  = s * 8 + srow;
            const int gs = sslot ^ (r & 7);
            const short* gb = Bm + (size_t)(n0 + r) * ldb + k0 + gs * 8;
            __builtin_amdgcn_global_load_lds(
                (const __attribute__((address_space(1))) void*)gb,
                (__attribute__((address_space(3))) void*)(&Bs[buf][s * 512]), 16, 0, 0);
        }
    };

    const int fr15 = lane & 15;
    const int fq   = lane >> 4;

    auto compute = [&](int buf) {
#pragma unroll
        for (int kk = 0; kk < 2; ++kk) {
            bf16x8 af[4], bff[FN];
            const int kob = kk * 64 + fq * 16;   // byte offset within 128B row
#pragma unroll
            for (int m = 0; m < 4; ++m) {
                const int r  = wr * 64 + m * 16 + fr15;
                const int sw = kob ^ ((r & 7) << 4);
                af[m] = *(const bf16x8*)(&As[buf][r * 64 + (sw >> 1)]);
            }
#pragma unroll
            for (int n = 0; n < FN; ++n) {
                const int r  = wc * (BN_T / 2) + n * 16 + fr15;
                const int sw = kob ^ ((r & 7) << 4);
                bff[n] = *(const bf16x8*)(&Bs[buf][r * 64 + (sw >> 1)]);
            }
#pragma unroll
            for (int m = 0; m < 4; ++m)
#pragma unroll
                for (int n = 0; n < FN; ++n)
                    acc[m][n] = __builtin_amdgcn_mfma_f32_16x16x32_bf16(af[m], bff[n], acc[m][n], 0, 0, 0);
        }
    };

    stage(0, 0);
    asm volatile("s_waitcnt vmcnt(0)" ::: "memory");
    __builtin_amdgcn_s_barrier();
    asm volatile("" ::: "memory");

    const int nt = K >> 6;
    int cur = 0;
    for (int t = 0; t < nt; ++t) {
        if (t + 1 < nt) stage(cur ^ 1, (t + 1) << 6);
        compute(cur);
        asm volatile("s_waitcnt vmcnt(0)" ::: "memory");
        __builtin_amdgcn_s_barrier();
        asm volatile("" ::: "memory");
        cur ^= 1;
    }

    const int fr = fr15;
#pragma unroll
    for (int m = 0; m < 4; ++m) {
#pragma unroll
        for (int n = 0; n < FN; ++n) {
#pragma unroll
            for (int j = 0; j < 4; ++j) {
                const int row = b0 + wr * 64 + m * 16 + fq * 4 + j;
                const int col = n0 + wc * (BN_T / 2) + n * 16 + fr;
                if (col < nbound) {
                    float v = acc[m][n][j];
                    if (bias0) v += bias0[biasZ * g + col];
                    C[(size_t)row * ldc + (size_t)col * cstride] = v;
                }
            }
        }
    }
}

// out[b,n] = p0[b,n] + p1[b,n] + bo[n]
__global__ __launch_bounds__(256) void reduce_out(
    const float* __restrict__ p0, const float* __restrict__ p1,
    const float* __restrict__ bo, float* __restrict__ out)
{
    const int n = blockIdx.x * 256 + threadIdx.x;
    const int b = blockIdx.y;
    if (n >= NOUT) return;
    out[(size_t)b * NOUT + n] = p0[(size_t)b * 1024 + n] + p1[(size_t)b * 1024 + n] + bo[n];
}

// ---------------------------------------------------------------------------
__global__ __launch_bounds__(256) void bn_stats(
    const float* __restrict__ Y, float* __restrict__ psum, float* __restrict__ psumsq)
{
    const int j  = blockIdx.x * 256 + threadIdx.x;
    const int r0 = blockIdx.y * RCHUNK;
    float s = 0.f, ss = 0.f;
    for (int r = 0; r < RCHUNK; ++r) {
        float v = Y[(size_t)(r0 + r) * Mdim + j];
        s += v; ss += v * v;
    }
    psum[blockIdx.y * Mdim + j]   = s;
    psumsq[blockIdx.y * Mdim + j] = ss;
}

__global__ __launch_bounds__(256) void bn_finalize(
    const float* __restrict__ psum, const float* __restrict__ psumsq,
    const float* __restrict__ gamma, const float* __restrict__ beta,
    float* __restrict__ scale, float* __restrict__ shift)
{
    const int j = blockIdx.x * 256 + threadIdx.x;
    if (j >= Mdim) return;
    float s = 0.f, ss = 0.f;
    for (int r = 0; r < NRCHUNK; ++r) {
        s  += psum[r * Mdim + j];
        ss += psumsq[r * Mdim + j];
    }
    const float mu  = s * (1.f / Bdim);
    const float var = ss * (1.f / Bdim) - mu * mu;
    const float sc  = gamma[j] * rsqrtf(var + 1e-5f);
    scale[j] = sc;
    shift[j] = beta[j] - mu * sc;
}

__global__ void alpha_softmax(const float* __restrict__ alpha, float* __restrict__ wsm)
{
    const int idx = threadIdx.x;
    if (idx >= Lnum * Pdim) return;
    const float* a = alpha + idx * Fdim;
    float mx = a[0];
#pragma unroll
    for (int f = 1; f < Fdim; ++f) mx = fmaxf(mx, a[f]);
    float e[Fdim]; float s = 0.f;
#pragma unroll
    for (int f = 0; f < Fdim; ++f) { e[f] = __expf(a[f] - mx); s += e[f]; }
    const float inv = 1.f / s;
#pragma unroll
    for (int f = 0; f < Fdim; ++f) wsm[idx * Fdim + f] = e[f] * inv;
}

// ---------------------------------------------------------------------------
// Fused normalize + permutation gather + combinact (K=2 closed form).
// One block per batch row; normalized row staged in LDS.
// MODE 0: grouped planes hg[g][b][p*512+q], c=q*4+g ; MODE 1: flat h[b][p*CH+c]
// ---------------------------------------------------------------------------
template<int MODE>
__global__ __launch_bounds__(256) void combinact_kernel(
    const float* __restrict__ Y, const float* __restrict__ scale,
    const float* __restrict__ shift, const int* __restrict__ perm,
    const float* __restrict__ wsm, short* __restrict__ out)
{
    __shared__ float yn[Mdim];
    const int b   = blockIdx.x;
    const int tid = threadIdx.x;

#pragma unroll
    for (int k = 0; k < 4; ++k) {
        const int i4 = k * 256 + tid;
        const float4 v  = *(const float4*)(Y + (size_t)b * Mdim + (size_t)i4 * 4);
        const float4 sc = *(const float4*)(scale + i4 * 4);
        const float4 sh = *(const float4*)(shift + i4 * 4);
        float4 r;
        r.x = v.x * sc.x + sh.x;
        r.y = v.y * sc.y + sh.y;
        r.z = v.z * sc.z + sh.z;
        r.w = v.w * sc.w + sh.w;
        *(float4*)(yn + i4 * 4) = r;
    }
    __syncthreads();

    float wv[Pdim][Fdim];
#pragma unroll
    for (int p = 0; p < Pdim; ++p)
#pragma unroll
        for (int f = 0; f < Fdim; ++f) wv[p][f] = wsm[p * Fdim + f];

#pragma unroll
    for (int k = 0; k < 8; ++k) {
        const int idx = k * 256 + tid;
        int c, g = 0, q = 0;
        if (MODE == 0) { g = idx >> 9; q = idx & 511; c = q * 4 + g; }
        else           { c = idx; }

#pragma unroll
        for (int p = 0; p < Pdim; ++p) {
            const int2 jj = *(const int2*)(perm + p * Mdim + 2 * c);
            const float z0 = yn[jj.x];
            const float z1 = yn[jj.y];

            const float mx  = fmaxf(z0, z1);
            const float pr  = z0 * z1;
            const float sgn = (pr > 0.f) ? 1.f : ((pr < 0.f) ? -1.f : 0.f);
            const float a1  = sgn * sqrtf(fabsf(pr) + 1e-12f);
            const float s0  = 1.f / (1.f + __expf(-z0));
            const float s1  = 1.f / (1.f + __expf(-z1));
            const float a2  = z0 * s0 * s1;
            const float a3  = sqrtf(z0 * z0 + z1 * z1 + 1e-12f);
            const float a4  = fmaxf(fabsf(z0), fabsf(z1));
            const float a5  = mx + log1pf(__expf(-fabsf(z0 - z1)));

            const float v = wv[p][0] * mx + wv[p][1] * a1 + wv[p][2] * a2 +
                            wv[p][3] * a3 + wv[p][4] * a4 + wv[p][5] * a5;

            if (MODE == 0)
                out[(size_t)g * ((size_t)Bdim * CIN) + (size_t)b * CIN + p * 512 + q] = f2bf(v);
            else
                out[(size_t)b * DNEXT + p * CH + c] = f2bf(v);
        }
    }
}

// ---------------------------------------------------------------------------
extern "C" void kernel_launch(void* const* d_in, const int* in_sizes, int n_in,
                              void* d_out, int out_size, void* d_ws, size_t ws_size,
                              hipStream_t stream)
{
    const float* x     = (const float*)d_in[0];
    const int*   perms = (const int*)  d_in[1];
    const float* W     = (const float*)d_in[2];
    const float* bvec  = (const float*)d_in[3];
    const float* gamma = (const float*)d_in[4];
    const float* beta  = (const float*)d_in[5];
    const float* alpha = (const float*)d_in[6];
    const float* Wo    = (const float*)d_in[7];
    const float* bo    = (const float*)d_in[8];
    float* out = (float*)d_out;

    char* ws = (char*)d_ws;
    float* y      = (float*)ws;                             // B*M f32
    short* hg     = (short*)(y + (size_t)Bdim * Mdim);      // G*B*CIN bf16
    short* hflat  = hg + (size_t)Gdim * Bdim * CIN;         // B*8192 bf16
    short* Wlb    = hflat + (size_t)Bdim * DNEXT;           // G*MG*CIN bf16 (aliased by out partials later)
    short* Wob    = Wlb + (size_t)Gdim * MG * CIN;          // 1024*8192 bf16
    float* psum   = (float*)(Wob + (size_t)1024 * DNEXT);
    float* psumsq = psum + (size_t)NRCHUNK * Mdim;
    float* scale  = psumsq + (size_t)NRCHUNK * Mdim;
    float* shift  = scale + Mdim;
    float* wsm    = shift + Mdim;

    float* part = (float*)Wlb;   // 2 x (B*1024) f32 = 16 MB, fits in Wlb's 32 MB

    alpha_softmax<<<1, 64, 0, stream>>>(alpha, wsm);
    convert_wo<<<(1024 * 1024) / 256, 256, 0, stream>>>(Wo, Wob);
    x_to_grouped<<<dim3(CIN / 256, Bdim), 256, 0, stream>>>(x, hg);

    const size_t planeA = (size_t)Bdim * CIN;
    const size_t planeB = (size_t)MG * CIN;

    for (int l = 0; l < Lnum; ++l) {
        convert_f32_bf16<<<(Gdim * MG * CIN / 8) / 256, 256, 0, stream>>>(
            W + (size_t)l * Gdim * MG * CIN, Wlb, Gdim * MG * CIN / 8);

        dim3 gg(MG / 128, Bdim / 128, Gdim);
        gemm_mfma<128><<<gg, 256, 0, stream>>>(
            hg, planeA, CIN, Wlb, planeB, CIN,
            bvec + (size_t)l * Gdim * MG, (size_t)MG,
            y, (size_t)1,
            CIN, Mdim, Gdim, MG);

        dim3 gs(Mdim / 256, NRCHUNK);
        bn_stats<<<gs, 256, 0, stream>>>(y, psum, psumsq);
        bn_finalize<<<Mdim / 256, 256, 0, stream>>>(
            psum, psumsq, gamma + (size_t)l * Mdim, beta + (size_t)l * Mdim, scale, shift);

        if (l < Lnum - 1)
            combinact_kernel<0><<<Bdim, 256, 0, stream>>>(
                y, scale, shift, perms + (size_t)l * Pdim * Mdim, wsm + l * Pdim * Fdim, hg);
        else
            combinact_kernel<1><<<Bdim, 256, 0, stream>>>(
                y, scale, shift, perms + (size_t)l * Pdim * Mdim, wsm + l * Pdim * Fdim, hflat);
    }

    // Output GEMM, split-K=2, partials then deterministic reduce.
    dim3 go(1024 / 64, Bdim / 128, 2);
    gemm_mfma<64><<<go, 256, 0, stream>>>(
        hflat, (size_t)4096, DNEXT, Wob, (size_t)4096, DNEXT,
        nullptr, 0,
        part, (size_t)Bdim * 1024,
        4096, 1024, 1, 1024);

    dim3 gr(4, Bdim);
    reduce_out<<<gr, 256, 0, stream>>>(part, part + (size_t)Bdim * 1024, bo, out);
}

// Round 5
// 442.359 us; speedup vs baseline: 7.0274x; 1.3463x over previous
//
#include <hip/hip_runtime.h>
#include <math.h>

#define Lnum 3
#define Mdim 4096
#define Pdim 4
#define Gdim 4
#define NIN 8192
#define NOUT 1000
#define Bdim 2048
#define Fdim 6
#define CIN 2048      // input channels per group (all layers)
#define MG 1024       // M / G
#define CH 2048       // M / K
#define DNEXT 8192
#define RCHUNK 128
#define NRCHUNK (Bdim / RCHUNK)

typedef short bf16x8 __attribute__((ext_vector_type(8)));
typedef float f32x4 __attribute__((ext_vector_type(4)));

__device__ __forceinline__ short f2bf(float f) {
    union { float f; unsigned u; } v; v.f = f;
    unsigned u = v.u;
    unsigned r = (u + 0x7fffu + ((u >> 16) & 1u)) >> 16;
    return (short)r;
}

// ---------------------------------------------------------------------------
__global__ __launch_bounds__(256) void convert_f32_bf16(
    const float* __restrict__ src, short* __restrict__ dst, int n8)
{
    int i = blockIdx.x * 256 + threadIdx.x;
    if (i >= n8) return;
    const float4* s = (const float4*)src + (size_t)i * 2;
    float4 v0 = s[0], v1 = s[1];
    bf16x8 o;
    o[0] = f2bf(v0.x); o[1] = f2bf(v0.y); o[2] = f2bf(v0.z); o[3] = f2bf(v0.w);
    o[4] = f2bf(v1.x); o[5] = f2bf(v1.y); o[6] = f2bf(v1.z); o[7] = f2bf(v1.w);
    *((bf16x8*)dst + i) = o;
}

// Wo (1000 x 8192) f32 -> padded (1024 x 8192) bf16, pad rows zero
__global__ __launch_bounds__(256) void convert_wo(
    const float* __restrict__ src, short* __restrict__ dst)
{
    int i = blockIdx.x * 256 + threadIdx.x;
    int row = i >> 10;
    bf16x8 o;
    if (row < NOUT) {
        const float4* s = (const float4*)(src + (size_t)row * DNEXT + (i & 1023) * 8);
        float4 v0 = s[0], v1 = s[1];
        o[0] = f2bf(v0.x); o[1] = f2bf(v0.y); o[2] = f2bf(v0.z); o[3] = f2bf(v0.w);
        o[4] = f2bf(v1.x); o[5] = f2bf(v1.y); o[6] = f2bf(v1.z); o[7] = f2bf(v1.w);
    } else {
        for (int j = 0; j < 8; ++j) o[j] = 0;
    }
    *((bf16x8*)dst + i) = o;
}

// x (B x 8192) f32 -> grouped bf16 planes hg[g][b][c] = x[b][4c+g]
__global__ __launch_bounds__(256) void x_to_grouped(
    const float* __restrict__ x, short* __restrict__ hg)
{
    const int c = blockIdx.x * 256 + threadIdx.x;
    const int b = blockIdx.y;
    float4 v = *(const float4*)(x + (size_t)b * NIN + 4 * c);
    const size_t plane = (size_t)Bdim * CIN;
    hg[0 * plane + (size_t)b * CIN + c] = f2bf(v.x);
    hg[1 * plane + (size_t)b * CIN + c] = f2bf(v.y);
    hg[2 * plane + (size_t)b * CIN + c] = f2bf(v.z);
    hg[3 * plane + (size_t)b * CIN + c] = f2bf(v.w);
}

// ---------------------------------------------------------------------------
// MFMA bf16 GEMM, double-buffered prefetch, BK=64, XOR-swizzled LDS.
// ---------------------------------------------------------------------------
template<int BN_T>
__global__ __launch_bounds__(256) void gemm_mfma(
    const short* __restrict__ A0, size_t aZ, int lda,
    const short* __restrict__ B0, size_t bZ, int ldb,
    const float* __restrict__ bias0, size_t biasZ,
    float* __restrict__ C0, size_t cZ,
    int K, int ldc, int cstride, int nbound)
{
    constexpr int FN = BN_T / 32;

    const int nx = gridDim.x, ny = gridDim.y;
    const int nwg = nx * ny * gridDim.z;
    const int lin = blockIdx.x + nx * (blockIdx.y + ny * blockIdx.z);
    int swz = (lin & 7) * (nwg >> 3) + (lin >> 3);
    const int bx = swz % nx; swz /= nx;
    const int by = swz % ny;
    const int g  = swz / ny;

    const short* A  = A0 + aZ * g;
    const short* Bm = B0 + bZ * g;
    float* C = C0 + cZ * g;

    const int n0 = bx * BN_T;
    const int b0 = by * 128;

    __shared__ short As[2][128 * 64];
    __shared__ short Bs[2][BN_T * 64];

    const int tid  = threadIdx.x;
    const int w    = tid >> 6;
    const int lane = tid & 63;
    const int wr = w >> 1, wc = w & 1;

    f32x4 acc[4][FN];
#pragma unroll
    for (int m = 0; m < 4; ++m)
#pragma unroll
        for (int n = 0; n < FN; ++n) acc[m][n] = (f32x4)0.f;

    const int srow  = lane >> 3;
    const int sslot = lane & 7;

    auto stage = [&](int buf, int k0) {
#pragma unroll
        for (int s = w; s < 16; s += 4) {
            const int r  = s * 8 + srow;
            const int gs = sslot ^ (r & 7);
            const short* ga = A + (size_t)(b0 + r) * lda + k0 + gs * 8;
            __builtin_amdgcn_global_load_lds(
                (const __attribute__((address_space(1))) void*)ga,
                (__attribute__((address_space(3))) void*)(&As[buf][s * 512]), 16, 0, 0);
        }
#pragma unroll
        for (int s = w; s < BN_T / 8; s += 4) {
            const int r  = s * 8 + srow;
            const int gs = sslot ^ (r & 7);
            const short* gb = Bm + (size_t)(n0 + r) * ldb + k0 + gs * 8;
            __builtin_amdgcn_global_load_lds(
                (const __attribute__((address_space(1))) void*)gb,
                (__attribute__((address_space(3))) void*)(&Bs[buf][s * 512]), 16, 0, 0);
        }
    };

    const int fr15 = lane & 15;
    const int fq   = lane >> 4;

    auto compute = [&](int buf) {
#pragma unroll
        for (int kk = 0; kk < 2; ++kk) {
            bf16x8 af[4], bff[FN];
            const int kob = kk * 64 + fq * 16;
#pragma unroll
            for (int m = 0; m < 4; ++m) {
                const int r  = wr * 64 + m * 16 + fr15;
                const int sw = kob ^ ((r & 7) << 4);
                af[m] = *(const bf16x8*)(&As[buf][r * 64 + (sw >> 1)]);
            }
#pragma unroll
            for (int n = 0; n < FN; ++n) {
                const int r  = wc * (BN_T / 2) + n * 16 + fr15;
                const int sw = kob ^ ((r & 7) << 4);
                bff[n] = *(const bf16x8*)(&Bs[buf][r * 64 + (sw >> 1)]);
            }
#pragma unroll
            for (int m = 0; m < 4; ++m)
#pragma unroll
                for (int n = 0; n < FN; ++n)
                    acc[m][n] = __builtin_amdgcn_mfma_f32_16x16x32_bf16(af[m], bff[n], acc[m][n], 0, 0, 0);
        }
    };

    stage(0, 0);
    asm volatile("s_waitcnt vmcnt(0)" ::: "memory");
    __builtin_amdgcn_s_barrier();
    asm volatile("" ::: "memory");

    const int nt = K >> 6;
    int cur = 0;
    for (int t = 0; t < nt; ++t) {
        if (t + 1 < nt) stage(cur ^ 1, (t + 1) << 6);
        compute(cur);
        asm volatile("s_waitcnt vmcnt(0)" ::: "memory");
        __builtin_amdgcn_s_barrier();
        asm volatile("" ::: "memory");
        cur ^= 1;
    }

    const int fr = fr15;
#pragma unroll
    for (int m = 0; m < 4; ++m) {
#pragma unroll
        for (int n = 0; n < FN; ++n) {
#pragma unroll
            for (int j = 0; j < 4; ++j) {
                const int row = b0 + wr * 64 + m * 16 + fq * 4 + j;
                const int col = n0 + wc * (BN_T / 2) + n * 16 + fr;
                if (col < nbound) {
                    float v = acc[m][n][j];
                    if (bias0) v += bias0[biasZ * g + col];
                    C[(size_t)row * ldc + (size_t)col * cstride] = v;
                }
            }
        }
    }
}

// out[b,n] = p0[b,n] + p1[b,n] + bo[n]
__global__ __launch_bounds__(256) void reduce_out(
    const float* __restrict__ p0, const float* __restrict__ p1,
    const float* __restrict__ bo, float* __restrict__ out)
{
    const int n = blockIdx.x * 256 + threadIdx.x;
    const int b = blockIdx.y;
    if (n >= NOUT) return;
    out[(size_t)b * NOUT + n] = p0[(size_t)b * 1024 + n] + p1[(size_t)b * 1024 + n] + bo[n];
}

// ---------------------------------------------------------------------------
__global__ __launch_bounds__(256) void bn_stats(
    const float* __restrict__ Y, float* __restrict__ psum, float* __restrict__ psumsq)
{
    const int j  = blockIdx.x * 256 + threadIdx.x;
    const int r0 = blockIdx.y * RCHUNK;
    float s = 0.f, ss = 0.f;
    for (int r = 0; r < RCHUNK; ++r) {
        float v = Y[(size_t)(r0 + r) * Mdim + j];
        s += v; ss += v * v;
    }
    psum[blockIdx.y * Mdim + j]   = s;
    psumsq[blockIdx.y * Mdim + j] = ss;
}

__global__ __launch_bounds__(256) void bn_finalize(
    const float* __restrict__ psum, const float* __restrict__ psumsq,
    const float* __restrict__ gamma, const float* __restrict__ beta,
    float* __restrict__ scale, float* __restrict__ shift)
{
    const int j = blockIdx.x * 256 + threadIdx.x;
    if (j >= Mdim) return;
    float s = 0.f, ss = 0.f;
    for (int r = 0; r < NRCHUNK; ++r) {
        s  += psum[r * Mdim + j];
        ss += psumsq[r * Mdim + j];
    }
    const float mu  = s * (1.f / Bdim);
    const float var = ss * (1.f / Bdim) - mu * mu;
    const float sc  = gamma[j] * rsqrtf(var + 1e-5f);
    scale[j] = sc;
    shift[j] = beta[j] - mu * sc;
}

__global__ void alpha_softmax(const float* __restrict__ alpha, float* __restrict__ wsm)
{
    const int idx = threadIdx.x;
    if (idx >= Lnum * Pdim) return;
    const float* a = alpha + idx * Fdim;
    float mx = a[0];
#pragma unroll
    for (int f = 1; f < Fdim; ++f) mx = fmaxf(mx, a[f]);
    float e[Fdim]; float s = 0.f;
#pragma unroll
    for (int f = 0; f < Fdim; ++f) { e[f] = __expf(a[f] - mx); s += e[f]; }
    const float inv = 1.f / s;
#pragma unroll
    for (int f = 0; f < Fdim; ++f) wsm[idx * Fdim + f] = e[f] * inv;
}

// ---------------------------------------------------------------------------
// Fused normalize + permutation gather + combinact (K=2 closed form).
// One block per batch row; normalized row staged in LDS. Activation math uses
// raw hw transcendentals (v_exp/v_log/v_rcp/v_sqrt) — error ~1e-6, far under
// the bf16 noise already present.
//   s0*s1 = rcp((1+e^-z0)(1+e^-z1))        [1 rcp instead of 2 precise divs]
//   lse   = mx + ln2 * log2(1 + 2^(-|d|*log2e))  [replaces log1pf libcall]
// MODE 0: grouped planes hg[g][b][p*512+q], c=q*4+g ; MODE 1: flat h[b][p*CH+c]
// ---------------------------------------------------------------------------
template<int MODE>
__global__ __launch_bounds__(256) void combinact_kernel(
    const float* __restrict__ Y, const float* __restrict__ scale,
    const float* __restrict__ shift, const int* __restrict__ perm,
    const float* __restrict__ wsm, short* __restrict__ out)
{
    __shared__ float yn[Mdim];
    const int b   = blockIdx.x;
    const int tid = threadIdx.x;

#pragma unroll
    for (int k = 0; k < 4; ++k) {
        const int i4 = k * 256 + tid;
        const float4 v  = *(const float4*)(Y + (size_t)b * Mdim + (size_t)i4 * 4);
        const float4 sc = *(const float4*)(scale + i4 * 4);
        const float4 sh = *(const float4*)(shift + i4 * 4);
        float4 r;
        r.x = v.x * sc.x + sh.x;
        r.y = v.y * sc.y + sh.y;
        r.z = v.z * sc.z + sh.z;
        r.w = v.w * sc.w + sh.w;
        *(float4*)(yn + i4 * 4) = r;
    }
    __syncthreads();

    float wv[Pdim][Fdim];
#pragma unroll
    for (int p = 0; p < Pdim; ++p)
#pragma unroll
        for (int f = 0; f < Fdim; ++f) wv[p][f] = wsm[p * Fdim + f];

    const float L2E = 1.44269504f;   // log2(e)
    const float LN2 = 0.69314718f;   // ln(2)

#pragma unroll
    for (int k = 0; k < 8; ++k) {
        const int idx = k * 256 + tid;
        int c, g = 0, q = 0;
        if (MODE == 0) { g = idx >> 9; q = idx & 511; c = q * 4 + g; }
        else           { c = idx; }

#pragma unroll
        for (int p = 0; p < Pdim; ++p) {
            const int2 jj = *(const int2*)(perm + p * Mdim + 2 * c);
            const float z0 = yn[jj.x];
            const float z1 = yn[jj.y];

            const float mx = fmaxf(z0, z1);
            const float pr = z0 * z1;
            const float a1 = copysignf(__builtin_amdgcn_sqrtf(fabsf(pr) + 1e-12f), pr);

            const float e0 = __builtin_amdgcn_exp2f(-L2E * z0);
            const float e1 = __builtin_amdgcn_exp2f(-L2E * z1);
            const float a2 = z0 * __builtin_amdgcn_rcpf((1.f + e0) * (1.f + e1));

            const float a3 = __builtin_amdgcn_sqrtf(z0 * z0 + z1 * z1 + 1e-12f);
            const float a4 = fmaxf(fabsf(z0), fabsf(z1));

            const float ed = __builtin_amdgcn_exp2f(-L2E * fabsf(z0 - z1));
            const float a5 = mx + LN2 * __builtin_amdgcn_logf(1.f + ed);

            const float v = wv[p][0] * mx + wv[p][1] * a1 + wv[p][2] * a2 +
                            wv[p][3] * a3 + wv[p][4] * a4 + wv[p][5] * a5;

            if (MODE == 0)
                out[(size_t)g * ((size_t)Bdim * CIN) + (size_t)b * CIN + p * 512 + q] = f2bf(v);
            else
                out[(size_t)b * DNEXT + p * CH + c] = f2bf(v);
        }
    }
}

// ---------------------------------------------------------------------------
extern "C" void kernel_launch(void* const* d_in, const int* in_sizes, int n_in,
                              void* d_out, int out_size, void* d_ws, size_t ws_size,
                              hipStream_t stream)
{
    const float* x     = (const float*)d_in[0];
    const int*   perms = (const int*)  d_in[1];
    const float* W     = (const float*)d_in[2];
    const float* bvec  = (const float*)d_in[3];
    const float* gamma = (const float*)d_in[4];
    const float* beta  = (const float*)d_in[5];
    const float* alpha = (const float*)d_in[6];
    const float* Wo    = (const float*)d_in[7];
    const float* bo    = (const float*)d_in[8];
    float* out = (float*)d_out;

    char* ws = (char*)d_ws;
    float* y      = (float*)ws;                             // B*M f32
    short* hg     = (short*)(y + (size_t)Bdim * Mdim);      // G*B*CIN bf16
    short* hflat  = hg + (size_t)Gdim * Bdim * CIN;         // B*8192 bf16
    short* Wlb    = hflat + (size_t)Bdim * DNEXT;           // G*MG*CIN bf16
    short* Wob    = Wlb + (size_t)Gdim * MG * CIN;          // 1024*8192 bf16
    float* psum   = (float*)(Wob + (size_t)1024 * DNEXT);
    float* psumsq = psum + (size_t)NRCHUNK * Mdim;
    float* scale  = psumsq + (size_t)NRCHUNK * Mdim;
    float* shift  = scale + Mdim;
    float* wsm    = shift + Mdim;

    float* part = (float*)Wlb;   // 2 x (B*1024) f32, aliases Wlb (dead by then)

    alpha_softmax<<<1, 64, 0, stream>>>(alpha, wsm);
    convert_wo<<<(1024 * 1024) / 256, 256, 0, stream>>>(Wo, Wob);
    x_to_grouped<<<dim3(CIN / 256, Bdim), 256, 0, stream>>>(x, hg);

    const size_t planeA = (size_t)Bdim * CIN;
    const size_t planeB = (size_t)MG * CIN;

    for (int l = 0; l < Lnum; ++l) {
        convert_f32_bf16<<<(Gdim * MG * CIN / 8) / 256, 256, 0, stream>>>(
            W + (size_t)l * Gdim * MG * CIN, Wlb, Gdim * MG * CIN / 8);

        dim3 gg(MG / 128, Bdim / 128, Gdim);
        gemm_mfma<128><<<gg, 256, 0, stream>>>(
            hg, planeA, CIN, Wlb, planeB, CIN,
            bvec + (size_t)l * Gdim * MG, (size_t)MG,
            y, (size_t)1,
            CIN, Mdim, Gdim, MG);

        dim3 gs(Mdim / 256, NRCHUNK);
        bn_stats<<<gs, 256, 0, stream>>>(y, psum, psumsq);
        bn_finalize<<<Mdim / 256, 256, 0, stream>>>(
            psum, psumsq, gamma + (size_t)l * Mdim, beta + (size_t)l * Mdim, scale, shift);

        if (l < Lnum - 1)
            combinact_kernel<0><<<Bdim, 256, 0, stream>>>(
                y, scale, shift, perms + (size_t)l * Pdim * Mdim, wsm + l * Pdim * Fdim, hg);
        else
            combinact_kernel<1><<<Bdim, 256, 0, stream>>>(
                y, scale, shift, perms + (size_t)l * Pdim * Mdim, wsm + l * Pdim * Fdim, hflat);
    }

    // Output GEMM, split-K=2, partials then deterministic reduce.
    dim3 go(1024 / 64, Bdim / 128, 2);
    gemm_mfma<64><<<go, 256, 0, stream>>>(
        hflat, (size_t)4096, DNEXT, Wob, (size_t)4096, DNEXT,
        nullptr, 0,
        part, (size_t)Bdim * 1024,
        4096, 1024, 1, 1024);

    dim3 gr(4, Bdim);
    reduce_out<<<gr, 256, 0, stream>>>(part, part + (size_t)Bdim * 1024, bo, out);
}

// Round 6
// 351.625 us; speedup vs baseline: 8.8407x; 1.2580x over previous
//
#include <hip/hip_runtime.h>
#include <math.h>

#define Lnum 3
#define Mdim 4096
#define Pdim 4
#define Gdim 4
#define NIN 8192
#define NOUT 1000
#define Bdim 2048
#define Fdim 6
#define CIN 2048      // input channels per group (all layers)
#define MG 1024       // M / G
#define CH 2048       // M / K
#define DNEXT 8192
#define RCHUNK 128
#define NRCHUNK (Bdim / RCHUNK)

typedef short bf16x8 __attribute__((ext_vector_type(8)));
typedef float f32x4 __attribute__((ext_vector_type(4)));

__device__ __forceinline__ short f2bf(float f) {
    union { float f; unsigned u; } v; v.f = f;
    unsigned u = v.u;
    unsigned r = (u + 0x7fffu + ((u >> 16) & 1u)) >> 16;
    return (short)r;
}

// ---------------------------------------------------------------------------
__global__ __launch_bounds__(256) void convert_f32_bf16(
    const float* __restrict__ src, short* __restrict__ dst, int n8)
{
    int i = blockIdx.x * 256 + threadIdx.x;
    if (i >= n8) return;
    const float4* s = (const float4*)src + (size_t)i * 2;
    float4 v0 = s[0], v1 = s[1];
    bf16x8 o;
    o[0] = f2bf(v0.x); o[1] = f2bf(v0.y); o[2] = f2bf(v0.z); o[3] = f2bf(v0.w);
    o[4] = f2bf(v1.x); o[5] = f2bf(v1.y); o[6] = f2bf(v1.z); o[7] = f2bf(v1.w);
    *((bf16x8*)dst + i) = o;
}

// Wo (1000 x 8192) f32 -> padded (1024 x 8192) bf16, pad rows zero
__global__ __launch_bounds__(256) void convert_wo(
    const float* __restrict__ src, short* __restrict__ dst)
{
    int i = blockIdx.x * 256 + threadIdx.x;
    int row = i >> 10;
    bf16x8 o;
    if (row < NOUT) {
        const float4* s = (const float4*)(src + (size_t)row * DNEXT + (i & 1023) * 8);
        float4 v0 = s[0], v1 = s[1];
        o[0] = f2bf(v0.x); o[1] = f2bf(v0.y); o[2] = f2bf(v0.z); o[3] = f2bf(v0.w);
        o[4] = f2bf(v1.x); o[5] = f2bf(v1.y); o[6] = f2bf(v1.z); o[7] = f2bf(v1.w);
    } else {
        for (int j = 0; j < 8; ++j) o[j] = 0;
    }
    *((bf16x8*)dst + i) = o;
}

// x (B x 8192) f32 -> grouped bf16 planes hg[g][b][c] = x[b][4c+g]
__global__ __launch_bounds__(256) void x_to_grouped(
    const float* __restrict__ x, short* __restrict__ hg)
{
    const int c = blockIdx.x * 256 + threadIdx.x;
    const int b = blockIdx.y;
    float4 v = *(const float4*)(x + (size_t)b * NIN + 4 * c);
    const size_t plane = (size_t)Bdim * CIN;
    hg[0 * plane + (size_t)b * CIN + c] = f2bf(v.x);
    hg[1 * plane + (size_t)b * CIN + c] = f2bf(v.y);
    hg[2 * plane + (size_t)b * CIN + c] = f2bf(v.z);
    hg[3 * plane + (size_t)b * CIN + c] = f2bf(v.w);
}

// perm value remap into grouped-y coordinates: j -> (j&3)*1024 + (j>>2)
__global__ __launch_bounds__(256) void remap_perms(
    const int* __restrict__ perm, int* __restrict__ perm_g, int n)
{
    int i = blockIdx.x * 256 + threadIdx.x;
    if (i >= n) return;
    int j = perm[i];
    perm_g[i] = ((j & 3) << 10) | (j >> 2);
}

// ---------------------------------------------------------------------------
// MFMA bf16 GEMM, double-buffered prefetch, BK=64, XOR-swizzled LDS.
// Tile 128 x BN_T, NWARP waves (2 x NWARP/2). C[row, n] += A[row,:]·B[n,:].
// Contiguous C stores (cstride==1 path used everywhere now).
// ---------------------------------------------------------------------------
template<int BN_T, int NWARP>
__global__ __launch_bounds__(NWARP * 64) void gemm_mfma(
    const short* __restrict__ A0, size_t aZ, int lda,
    const short* __restrict__ B0, size_t bZ, int ldb,
    const float* __restrict__ bias0, size_t biasZ,
    float* __restrict__ C0, size_t cZ,
    int K, int ldc, int nbound)
{
    constexpr int NT   = NWARP * 64;
    constexpr int WCN  = NWARP / 2;       // waves along N
    constexpr int WCOL = BN_T / WCN;      // cols per wave
    constexpr int FN   = WCOL / 16;       // 16-col frags per wave

    // XCD-aware swizzle (nwg % 8 == 0 in all our launches)
    const int nx = gridDim.x, ny = gridDim.y;
    const int nwg = nx * ny * gridDim.z;
    const int lin = blockIdx.x + nx * (blockIdx.y + ny * blockIdx.z);
    int swz = (lin & 7) * (nwg >> 3) + (lin >> 3);
    const int bx = swz % nx; swz /= nx;
    const int by = swz % ny;
    const int g  = swz / ny;

    const short* A  = A0 + aZ * g;
    const short* Bm = B0 + bZ * g;
    float* C = C0 + cZ * g;

    const int n0 = bx * BN_T;
    const int b0 = by * 128;

    __shared__ short As[2][128 * 64];
    __shared__ short Bs[2][BN_T * 64];

    const int tid  = threadIdx.x;
    const int w    = tid >> 6;
    const int lane = tid & 63;
    const int wr = w / WCN, wc = w % WCN;

    f32x4 acc[4][FN];
#pragma unroll
    for (int m = 0; m < 4; ++m)
#pragma unroll
        for (int n = 0; n < FN; ++n) acc[m][n] = (f32x4)0.f;

    // Stage one K-tile into buffer `buf`. Linear LDS dest; global source slot
    // XOR-swizzled (slot ^ (row&7)), matching the swizzled ds_read below.
    auto stage = [&](int buf, int k0) {
#pragma unroll
        for (int idx = tid; idx < 128 * 8; idx += NT) {
            const int r = idx >> 3, slot = idx & 7;
            const int gs = slot ^ (r & 7);
            const short* ga = A + (size_t)(b0 + r) * lda + k0 + gs * 8;
            __builtin_amdgcn_global_load_lds(
                (const __attribute__((address_space(1))) void*)ga,
                (__attribute__((address_space(3))) void*)(&As[buf][idx * 8]), 16, 0, 0);
        }
#pragma unroll
        for (int idx = tid; idx < BN_T * 8; idx += NT) {
            const int r = idx >> 3, slot = idx & 7;
            const int gs = slot ^ (r & 7);
            const short* gb = Bm + (size_t)(n0 + r) * ldb + k0 + gs * 8;
            __builtin_amdgcn_global_load_lds(
                (const __attribute__((address_space(1))) void*)gb,
                (__attribute__((address_space(3))) void*)(&Bs[buf][idx * 8]), 16, 0, 0);
        }
    };

    const int fr15 = lane & 15;
    const int fq   = lane >> 4;

    auto compute = [&](int buf) {
#pragma unroll
        for (int kk = 0; kk < 2; ++kk) {
            bf16x8 af[4], bff[FN];
            const int kob = kk * 64 + fq * 16;   // byte offset within 128B row
#pragma unroll
            for (int m = 0; m < 4; ++m) {
                const int r  = wr * 64 + m * 16 + fr15;
                const int sw = kob ^ ((r & 7) << 4);
                af[m] = *(const bf16x8*)(&As[buf][r * 64 + (sw >> 1)]);
            }
#pragma unroll
            for (int n = 0; n < FN; ++n) {
                const int r  = wc * WCOL + n * 16 + fr15;
                const int sw = kob ^ ((r & 7) << 4);
                bff[n] = *(const bf16x8*)(&Bs[buf][r * 64 + (sw >> 1)]);
            }
#pragma unroll
            for (int m = 0; m < 4; ++m)
#pragma unroll
                for (int n = 0; n < FN; ++n)
                    acc[m][n] = __builtin_amdgcn_mfma_f32_16x16x32_bf16(af[m], bff[n], acc[m][n], 0, 0, 0);
        }
    };

    stage(0, 0);
    asm volatile("s_waitcnt vmcnt(0)" ::: "memory");
    __builtin_amdgcn_s_barrier();
    asm volatile("" ::: "memory");

    const int nt = K >> 6;
    int cur = 0;
    for (int t = 0; t < nt; ++t) {
        if (t + 1 < nt) stage(cur ^ 1, (t + 1) << 6);
        compute(cur);
        asm volatile("s_waitcnt vmcnt(0)" ::: "memory");
        __builtin_amdgcn_s_barrier();
        asm volatile("" ::: "memory");
        cur ^= 1;
    }

#pragma unroll
    for (int m = 0; m < 4; ++m) {
#pragma unroll
        for (int n = 0; n < FN; ++n) {
#pragma unroll
            for (int j = 0; j < 4; ++j) {
                const int row = b0 + wr * 64 + m * 16 + fq * 4 + j;
                const int col = n0 + wc * WCOL + n * 16 + fr15;
                if (col < nbound) {
                    float v = acc[m][n][j];
                    if (bias0) v += bias0[biasZ * g + col];
                    C[(size_t)row * ldc + col] = v;
                }
            }
        }
    }
}

// out[b,n] = sum_z p[z][b,n] + bo[n], 4 split-K partials
__global__ __launch_bounds__(256) void reduce_out(
    const float* __restrict__ part, const float* __restrict__ bo,
    float* __restrict__ out)
{
    const int n = blockIdx.x * 256 + threadIdx.x;
    const int b = blockIdx.y;
    if (n >= NOUT) return;
    const size_t S = (size_t)Bdim * 1024;
    const size_t i = (size_t)b * 1024 + n;
    out[(size_t)b * NOUT + n] =
        part[i] + part[S + i] + part[2 * S + i] + part[3 * S + i] + bo[n];
}

// ---------------------------------------------------------------------------
__global__ __launch_bounds__(256) void bn_stats(
    const float* __restrict__ Y, float* __restrict__ psum, float* __restrict__ psumsq)
{
    const int j  = blockIdx.x * 256 + threadIdx.x;
    const int r0 = blockIdx.y * RCHUNK;
    float s = 0.f, ss = 0.f;
    for (int r = 0; r < RCHUNK; ++r) {
        float v = Y[(size_t)(r0 + r) * Mdim + j];
        s += v; ss += v * v;
    }
    psum[blockIdx.y * Mdim + j]   = s;
    psumsq[blockIdx.y * Mdim + j] = ss;
}

// Columns are in GROUPED order jg = g*1024+m  (orig j = (jg&1023)*4 + jg>>10)
__global__ __launch_bounds__(256) void bn_finalize(
    const float* __restrict__ psum, const float* __restrict__ psumsq,
    const float* __restrict__ gamma, const float* __restrict__ beta,
    float* __restrict__ scale, float* __restrict__ shift)
{
    const int jg = blockIdx.x * 256 + threadIdx.x;
    if (jg >= Mdim) return;
    const int j = ((jg & 1023) << 2) | (jg >> 10);
    float s = 0.f, ss = 0.f;
    for (int r = 0; r < NRCHUNK; ++r) {
        s  += psum[r * Mdim + jg];
        ss += psumsq[r * Mdim + jg];
    }
    const float mu  = s * (1.f / Bdim);
    const float var = ss * (1.f / Bdim) - mu * mu;
    const float sc  = gamma[j] * rsqrtf(var + 1e-5f);
    scale[jg] = sc;
    shift[jg] = beta[j] - mu * sc;
}

__global__ void alpha_softmax(const float* __restrict__ alpha, float* __restrict__ wsm)
{
    const int idx = threadIdx.x;
    if (idx >= Lnum * Pdim) return;
    const float* a = alpha + idx * Fdim;
    float mx = a[0];
#pragma unroll
    for (int f = 1; f < Fdim; ++f) mx = fmaxf(mx, a[f]);
    float e[Fdim]; float s = 0.f;
#pragma unroll
    for (int f = 0; f < Fdim; ++f) { e[f] = __expf(a[f] - mx); s += e[f]; }
    const float inv = 1.f / s;
#pragma unroll
    for (int f = 0; f < Fdim; ++f) wsm[idx * Fdim + f] = e[f] * inv;
}

// ---------------------------------------------------------------------------
// Fused normalize + permutation gather + combinact (K=2 closed form).
// Y is in grouped layout; perm_g holds pre-remapped (grouped) indices.
// MODE 0: grouped planes hg[g][b][p*512+q], c=q*4+g ; MODE 1: flat h[b][p*CH+c]
// ---------------------------------------------------------------------------
template<int MODE>
__global__ __launch_bounds__(256) void combinact_kernel(
    const float* __restrict__ Y, const float* __restrict__ scale,
    const float* __restrict__ shift, const int* __restrict__ perm,
    const float* __restrict__ wsm, short* __restrict__ out)
{
    __shared__ float yn[Mdim];
    const int b   = blockIdx.x;
    const int tid = threadIdx.x;

#pragma unroll
    for (int k = 0; k < 4; ++k) {
        const int i4 = k * 256 + tid;
        const float4 v  = *(const float4*)(Y + (size_t)b * Mdim + (size_t)i4 * 4);
        const float4 sc = *(const float4*)(scale + i4 * 4);
        const float4 sh = *(const float4*)(shift + i4 * 4);
        float4 r;
        r.x = v.x * sc.x + sh.x;
        r.y = v.y * sc.y + sh.y;
        r.z = v.z * sc.z + sh.z;
        r.w = v.w * sc.w + sh.w;
        *(float4*)(yn + i4 * 4) = r;
    }
    __syncthreads();

    float wv[Pdim][Fdim];
#pragma unroll
    for (int p = 0; p < Pdim; ++p)
#pragma unroll
        for (int f = 0; f < Fdim; ++f) wv[p][f] = wsm[p * Fdim + f];

    const float L2E = 1.44269504f;
    const float LN2 = 0.69314718f;

#pragma unroll
    for (int k = 0; k < 8; ++k) {
        const int idx = k * 256 + tid;
        int c, g = 0, q = 0;
        if (MODE == 0) { g = idx >> 9; q = idx & 511; c = q * 4 + g; }
        else           { c = idx; }

#pragma unroll
        for (int p = 0; p < Pdim; ++p) {
            const int2 jj = *(const int2*)(perm + p * Mdim + 2 * c);
            const float z0 = yn[jj.x];
            const float z1 = yn[jj.y];

            const float mx = fmaxf(z0, z1);
            const float pr = z0 * z1;
            const float a1 = copysignf(__builtin_amdgcn_sqrtf(fabsf(pr) + 1e-12f), pr);

            const float e0 = __builtin_amdgcn_exp2f(-L2E * z0);
            const float e1 = __builtin_amdgcn_exp2f(-L2E * z1);
            const float a2 = z0 * __builtin_amdgcn_rcpf((1.f + e0) * (1.f + e1));

            const float a3 = __builtin_amdgcn_sqrtf(z0 * z0 + z1 * z1 + 1e-12f);
            const float a4 = fmaxf(fabsf(z0), fabsf(z1));

            const float ed = __builtin_amdgcn_exp2f(-L2E * fabsf(z0 - z1));
            const float a5 = mx + LN2 * __builtin_amdgcn_logf(1.f + ed);

            const float v = wv[p][0] * mx + wv[p][1] * a1 + wv[p][2] * a2 +
                            wv[p][3] * a3 + wv[p][4] * a4 + wv[p][5] * a5;

            if (MODE == 0)
                out[(size_t)g * ((size_t)Bdim * CIN) + (size_t)b * CIN + p * 512 + q] = f2bf(v);
            else
                out[(size_t)b * DNEXT + p * CH + c] = f2bf(v);
        }
    }
}

// ---------------------------------------------------------------------------
extern "C" void kernel_launch(void* const* d_in, const int* in_sizes, int n_in,
                              void* d_out, int out_size, void* d_ws, size_t ws_size,
                              hipStream_t stream)
{
    const float* x     = (const float*)d_in[0];
    const int*   perms = (const int*)  d_in[1];
    const float* W     = (const float*)d_in[2];
    const float* bvec  = (const float*)d_in[3];
    const float* gamma = (const float*)d_in[4];
    const float* beta  = (const float*)d_in[5];
    const float* alpha = (const float*)d_in[6];
    const float* Wo    = (const float*)d_in[7];
    const float* bo    = (const float*)d_in[8];
    float* out = (float*)d_out;

    char* ws = (char*)d_ws;
    float* y      = (float*)ws;                             // B*M f32 (grouped cols)
    short* hg     = (short*)(y + (size_t)Bdim * Mdim);      // G*B*CIN bf16
    short* hflat  = hg + (size_t)Gdim * Bdim * CIN;         // B*8192 bf16
    short* Wlb    = hflat + (size_t)Bdim * DNEXT;           // G*MG*CIN bf16
    short* Wob    = Wlb + (size_t)Gdim * MG * CIN;          // 1024*8192 bf16
    float* psum   = (float*)(Wob + (size_t)1024 * DNEXT);
    float* psumsq = psum + (size_t)NRCHUNK * Mdim;
    float* scale  = psumsq + (size_t)NRCHUNK * Mdim;
    float* shift  = scale + Mdim;
    float* wsm    = shift + Mdim;
    int*   perm_g = (int*)(wsm + Lnum * Pdim * Fdim);       // L*P*M ints

    float* part = (float*)hg;   // 4 x (B*1024) f32 = 32 MB; hg dead by out-GEMM

    alpha_softmax<<<1, 64, 0, stream>>>(alpha, wsm);
    remap_perms<<<(Lnum * Pdim * Mdim) / 256, 256, 0, stream>>>(
        perms, perm_g, Lnum * Pdim * Mdim);
    convert_wo<<<(1024 * 1024) / 256, 256, 0, stream>>>(Wo, Wob);
    x_to_grouped<<<dim3(CIN / 256, Bdim), 256, 0, stream>>>(x, hg);

    const size_t planeA = (size_t)Bdim * CIN;
    const size_t planeB = (size_t)MG * CIN;

    for (int l = 0; l < Lnum; ++l) {
        convert_f32_bf16<<<(Gdim * MG * CIN / 8) / 256, 256, 0, stream>>>(
            W + (size_t)l * Gdim * MG * CIN, Wlb, Gdim * MG * CIN / 8);

        // y[b][g*1024+m] — contiguous stores (cZ = 1024 selects group column band)
        dim3 gg(MG / 128, Bdim / 128, Gdim);
        gemm_mfma<128, 8><<<gg, 512, 0, stream>>>(
            hg, planeA, CIN, Wlb, planeB, CIN,
            bvec + (size_t)l * Gdim * MG, (size_t)MG,
            y, (size_t)MG,
            CIN, Mdim, MG);

        dim3 gs(Mdim / 256, NRCHUNK);
        bn_stats<<<gs, 256, 0, stream>>>(y, psum, psumsq);
        bn_finalize<<<Mdim / 256, 256, 0, stream>>>(
            psum, psumsq, gamma + (size_t)l * Mdim, beta + (size_t)l * Mdim, scale, shift);

        if (l < Lnum - 1)
            combinact_kernel<0><<<Bdim, 256, 0, stream>>>(
                y, scale, shift, perm_g + (size_t)l * Pdim * Mdim, wsm + l * Pdim * Fdim, hg);
        else
            combinact_kernel<1><<<Bdim, 256, 0, stream>>>(
                y, scale, shift, perm_g + (size_t)l * Pdim * Mdim, wsm + l * Pdim * Fdim, hflat);
    }

    // Output GEMM, split-K=4 (K=2048 each), partials in hg, then reduce.
    dim3 go(1024 / 128, Bdim / 128, 4);
    gemm_mfma<128, 8><<<go, 512, 0, stream>>>(
        hflat, (size_t)2048, DNEXT, Wob, (size_t)2048, DNEXT,
        nullptr, 0,
        part, (size_t)Bdim * 1024,
        2048, 1024, 1024);

    dim3 gr(4, Bdim);
    reduce_out<<<gr, 256, 0, stream>>>(part, bo, out);
}

// Round 7
// 315.948 us; speedup vs baseline: 9.8390x; 1.1129x over previous
//
#include <hip/hip_runtime.h>
#include <math.h>

#define Lnum 3
#define Mdim 4096
#define Pdim 4
#define Gdim 4
#define NIN 8192
#define NOUT 1000
#define Bdim 2048
#define Fdim 6
#define CIN 2048      // input channels per group (all layers)
#define MG 1024       // M / G
#define CH 2048       // M / K
#define DNEXT 8192
#define NRCHUNK (Bdim / 128)   // 16 row-blocks of 128 = GEMM tile rows

typedef short bf16x8 __attribute__((ext_vector_type(8)));
typedef float f32x4 __attribute__((ext_vector_type(4)));

__device__ __forceinline__ short f2bf(float f) {
    union { float f; unsigned u; } v; v.f = f;
    unsigned u = v.u;
    unsigned r = (u + 0x7fffu + ((u >> 16) & 1u)) >> 16;
    return (short)r;
}
__device__ __forceinline__ float bf2f(short h) {
    union { unsigned u; float f; } x;
    x.u = ((unsigned)(unsigned short)h) << 16;
    return x.f;
}

// ---------------------------------------------------------------------------
__global__ __launch_bounds__(256) void convert_f32_bf16(
    const float* __restrict__ src, short* __restrict__ dst, int n8)
{
    int i = blockIdx.x * 256 + threadIdx.x;
    if (i >= n8) return;
    const float4* s = (const float4*)src + (size_t)i * 2;
    float4 v0 = s[0], v1 = s[1];
    bf16x8 o;
    o[0] = f2bf(v0.x); o[1] = f2bf(v0.y); o[2] = f2bf(v0.z); o[3] = f2bf(v0.w);
    o[4] = f2bf(v1.x); o[5] = f2bf(v1.y); o[6] = f2bf(v1.z); o[7] = f2bf(v1.w);
    *((bf16x8*)dst + i) = o;
}

// Wo (1000 x 8192) f32 -> padded (1024 x 8192) bf16, pad rows zero
__global__ __launch_bounds__(256) void convert_wo(
    const float* __restrict__ src, short* __restrict__ dst)
{
    int i = blockIdx.x * 256 + threadIdx.x;
    int row = i >> 10;
    bf16x8 o;
    if (row < NOUT) {
        const float4* s = (const float4*)(src + (size_t)row * DNEXT + (i & 1023) * 8);
        float4 v0 = s[0], v1 = s[1];
        o[0] = f2bf(v0.x); o[1] = f2bf(v0.y); o[2] = f2bf(v0.z); o[3] = f2bf(v0.w);
        o[4] = f2bf(v1.x); o[5] = f2bf(v1.y); o[6] = f2bf(v1.z); o[7] = f2bf(v1.w);
    } else {
        for (int j = 0; j < 8; ++j) o[j] = 0;
    }
    *((bf16x8*)dst + i) = o;
}

// x (B x 8192) f32 -> grouped bf16 planes hg[g][b][c] = x[b][4c+g]
__global__ __launch_bounds__(256) void x_to_grouped(
    const float* __restrict__ x, short* __restrict__ hg)
{
    const int c = blockIdx.x * 256 + threadIdx.x;
    const int b = blockIdx.y;
    float4 v = *(const float4*)(x + (size_t)b * NIN + 4 * c);
    const size_t plane = (size_t)Bdim * CIN;
    hg[0 * plane + (size_t)b * CIN + c] = f2bf(v.x);
    hg[1 * plane + (size_t)b * CIN + c] = f2bf(v.y);
    hg[2 * plane + (size_t)b * CIN + c] = f2bf(v.z);
    hg[3 * plane + (size_t)b * CIN + c] = f2bf(v.w);
}

// perm value remap into grouped-y coordinates: j -> (j&3)*1024 + (j>>2)
__global__ __launch_bounds__(256) void remap_perms(
    const int* __restrict__ perm, int* __restrict__ perm_g, int n)
{
    int i = blockIdx.x * 256 + threadIdx.x;
    if (i >= n) return;
    int j = perm[i];
    perm_g[i] = ((j & 3) << 10) | (j >> 2);
}

// ---------------------------------------------------------------------------
// MFMA bf16 GEMM, double-buffered prefetch, BK=64, XOR-swizzled LDS.
// Tile 128 x BN_T, NWARP waves (2 x NWARP/2). C[row,n] = A[row,:]·B[n,:]+bias.
// CT = short (bf16 store) or float. If STATS: per-column partial sum/sumsq of
// the stored tile is reduced across the block (LDS) and written to
// psum/psumsq[by * Mdim + g*sgz + n0 + col] — deterministic (1 writer/slot).
// ---------------------------------------------------------------------------
template<int BN_T, int NWARP, bool STATS, typename CT>
__global__ __launch_bounds__(NWARP * 64) void gemm_mfma(
    const short* __restrict__ A0, size_t aZ, int lda,
    const short* __restrict__ B0, size_t bZ, int ldb,
    const float* __restrict__ bias0, size_t biasZ,
    CT* __restrict__ C0, size_t cZ,
    int K, int ldc, int nbound,
    float* __restrict__ psum, float* __restrict__ psumsq, int sgz)
{
    constexpr int NT   = NWARP * 64;
    constexpr int WCN  = NWARP / 2;       // waves along N
    constexpr int WCOL = BN_T / WCN;      // cols per wave
    constexpr int FN   = WCOL / 16;       // 16-col frags per wave

    // XCD-aware swizzle (nwg % 8 == 0 in all our launches)
    const int nx = gridDim.x, ny = gridDim.y;
    const int nwg = nx * ny * gridDim.z;
    const int lin = blockIdx.x + nx * (blockIdx.y + ny * blockIdx.z);
    int swz = (lin & 7) * (nwg >> 3) + (lin >> 3);
    const int bx = swz % nx; swz /= nx;
    const int by = swz % ny;
    const int g  = swz / ny;

    const short* A  = A0 + aZ * g;
    const short* Bm = B0 + bZ * g;
    CT* C = C0 + cZ * g;

    const int n0 = bx * BN_T;
    const int b0 = by * 128;

    __shared__ short As[2][128 * 64];
    __shared__ short Bs[2][BN_T * 64];

    const int tid  = threadIdx.x;
    const int w    = tid >> 6;
    const int lane = tid & 63;
    const int wr = w / WCN, wc = w % WCN;

    f32x4 acc[4][FN];
#pragma unroll
    for (int m = 0; m < 4; ++m)
#pragma unroll
        for (int n = 0; n < FN; ++n) acc[m][n] = (f32x4)0.f;

    auto stage = [&](int buf, int k0) {
#pragma unroll
        for (int idx = tid; idx < 128 * 8; idx += NT) {
            const int r = idx >> 3, slot = idx & 7;
            const int gs = slot ^ (r & 7);
            const short* ga = A + (size_t)(b0 + r) * lda + k0 + gs * 8;
            __builtin_amdgcn_global_load_lds(
                (const __attribute__((address_space(1))) void*)ga,
                (__attribute__((address_space(3))) void*)(&As[buf][idx * 8]), 16, 0, 0);
        }
#pragma unroll
        for (int idx = tid; idx < BN_T * 8; idx += NT) {
            const int r = idx >> 3, slot = idx & 7;
            const int gs = slot ^ (r & 7);
            const short* gb = Bm + (size_t)(n0 + r) * ldb + k0 + gs * 8;
            __builtin_amdgcn_global_load_lds(
                (const __attribute__((address_space(1))) void*)gb,
                (__attribute__((address_space(3))) void*)(&Bs[buf][idx * 8]), 16, 0, 0);
        }
    };

    const int fr15 = lane & 15;
    const int fq   = lane >> 4;

    auto compute = [&](int buf) {
#pragma unroll
        for (int kk = 0; kk < 2; ++kk) {
            bf16x8 af[4], bff[FN];
            const int kob = kk * 64 + fq * 16;
#pragma unroll
            for (int m = 0; m < 4; ++m) {
                const int r  = wr * 64 + m * 16 + fr15;
                const int sw = kob ^ ((r & 7) << 4);
                af[m] = *(const bf16x8*)(&As[buf][r * 64 + (sw >> 1)]);
            }
#pragma unroll
            for (int n = 0; n < FN; ++n) {
                const int r  = wc * WCOL + n * 16 + fr15;
                const int sw = kob ^ ((r & 7) << 4);
                bff[n] = *(const bf16x8*)(&Bs[buf][r * 64 + (sw >> 1)]);
            }
#pragma unroll
            for (int m = 0; m < 4; ++m)
#pragma unroll
                for (int n = 0; n < FN; ++n)
                    acc[m][n] = __builtin_amdgcn_mfma_f32_16x16x32_bf16(af[m], bff[n], acc[m][n], 0, 0, 0);
        }
    };

    stage(0, 0);
    asm volatile("s_waitcnt vmcnt(0)" ::: "memory");
    __builtin_amdgcn_s_barrier();
    asm volatile("" ::: "memory");

    const int nt = K >> 6;
    int cur = 0;
    for (int t = 0; t < nt; ++t) {
        if (t + 1 < nt) stage(cur ^ 1, (t + 1) << 6);
        compute(cur);
        asm volatile("s_waitcnt vmcnt(0)" ::: "memory");
        __builtin_amdgcn_s_barrier();
        asm volatile("" ::: "memory");
        cur ^= 1;
    }

    float s[FN], ss[FN];
#pragma unroll
    for (int n = 0; n < FN; ++n) { s[n] = 0.f; ss[n] = 0.f; }

#pragma unroll
    for (int m = 0; m < 4; ++m) {
#pragma unroll
        for (int n = 0; n < FN; ++n) {
#pragma unroll
            for (int j = 0; j < 4; ++j) {
                const int row = b0 + wr * 64 + m * 16 + fq * 4 + j;
                const int col = n0 + wc * WCOL + n * 16 + fr15;
                if (col < nbound) {
                    float v = acc[m][n][j];
                    if (bias0) v += bias0[biasZ * g + col];
                    C[(size_t)row * ldc + col] = (CT)(sizeof(CT) == 2 ? (CT)f2bf(v) : (CT)v);
                    if (STATS) { s[n] += v; ss[n] += v * v; }
                }
            }
        }
    }

    if (STATS) {
        // LDS scratch (K-loop done): [BN_T cols][8 slots] for sum and sumsq
        float* sum_lds = (float*)&As[0][0];
        float* ssq_lds = sum_lds + BN_T * 8;
        const int slot = wr * 4 + fq;
#pragma unroll
        for (int n = 0; n < FN; ++n) {
            const int cl = wc * WCOL + n * 16 + fr15;
            sum_lds[cl * 8 + slot] = s[n];
            ssq_lds[cl * 8 + slot] = ss[n];
        }
        __syncthreads();
        for (int cl = tid; cl < BN_T; cl += NT) {
            float a = 0.f, b = 0.f;
#pragma unroll
            for (int q = 0; q < 8; ++q) {
                a += sum_lds[cl * 8 + q];
                b += ssq_lds[cl * 8 + q];
            }
            const size_t o = (size_t)by * Mdim + g * sgz + n0 + cl;
            psum[o]   = a;
            psumsq[o] = b;
        }
    }
}

// out[b,n] = sum_z p[z][b,n] + bo[n], 4 split-K partials
__global__ __launch_bounds__(256) void reduce_out(
    const float* __restrict__ part, const float* __restrict__ bo,
    float* __restrict__ out)
{
    const int n = blockIdx.x * 256 + threadIdx.x;
    const int b = blockIdx.y;
    if (n >= NOUT) return;
    const size_t S = (size_t)Bdim * 1024;
    const size_t i = (size_t)b * 1024 + n;
    out[(size_t)b * NOUT + n] =
        part[i] + part[S + i] + part[2 * S + i] + part[3 * S + i] + bo[n];
}

// ---------------------------------------------------------------------------
// Columns are in GROUPED order jg = g*1024+m  (orig j = (jg&1023)*4 + jg>>10)
__global__ __launch_bounds__(256) void bn_finalize(
    const float* __restrict__ psum, const float* __restrict__ psumsq,
    const float* __restrict__ gamma, const float* __restrict__ beta,
    float* __restrict__ scale, float* __restrict__ shift)
{
    const int jg = blockIdx.x * 256 + threadIdx.x;
    if (jg >= Mdim) return;
    const int j = ((jg & 1023) << 2) | (jg >> 10);
    float s = 0.f, ss = 0.f;
    for (int r = 0; r < NRCHUNK; ++r) {
        s  += psum[r * Mdim + jg];
        ss += psumsq[r * Mdim + jg];
    }
    const float mu  = s * (1.f / Bdim);
    const float var = ss * (1.f / Bdim) - mu * mu;
    const float sc  = gamma[j] * rsqrtf(var + 1e-5f);
    scale[jg] = sc;
    shift[jg] = beta[j] - mu * sc;
}

__global__ void alpha_softmax(const float* __restrict__ alpha, float* __restrict__ wsm)
{
    const int idx = threadIdx.x;
    if (idx >= Lnum * Pdim) return;
    const float* a = alpha + idx * Fdim;
    float mx = a[0];
#pragma unroll
    for (int f = 1; f < Fdim; ++f) mx = fmaxf(mx, a[f]);
    float e[Fdim]; float s = 0.f;
#pragma unroll
    for (int f = 0; f < Fdim; ++f) { e[f] = __expf(a[f] - mx); s += e[f]; }
    const float inv = 1.f / s;
#pragma unroll
    for (int f = 0; f < Fdim; ++f) wsm[idx * Fdim + f] = e[f] * inv;
}

// ---------------------------------------------------------------------------
// Fused normalize + permutation gather + combinact (K=2 closed form).
// Y is bf16 in grouped layout; perm holds pre-remapped (grouped) indices.
// MODE 0: grouped planes hg[g][b][p*512+q], c=q*4+g ; MODE 1: flat h[b][p*CH+c]
// ---------------------------------------------------------------------------
template<int MODE>
__global__ __launch_bounds__(256) void combinact_kernel(
    const short* __restrict__ Y, const float* __restrict__ scale,
    const float* __restrict__ shift, const int* __restrict__ perm,
    const float* __restrict__ wsm, short* __restrict__ out)
{
    __shared__ float yn[Mdim];
    const int b   = blockIdx.x;
    const int tid = threadIdx.x;

#pragma unroll
    for (int k = 0; k < 2; ++k) {
        const int i8 = k * 256 + tid;           // 512 chunks of 8
        bf16x8 v = *((const bf16x8*)(Y + (size_t)b * Mdim) + i8);
        float4 sc0 = *(const float4*)(scale + i8 * 8);
        float4 sc1 = *(const float4*)(scale + i8 * 8 + 4);
        float4 sh0 = *(const float4*)(shift + i8 * 8);
        float4 sh1 = *(const float4*)(shift + i8 * 8 + 4);
        float* o = yn + i8 * 8;
        o[0] = bf2f(v[0]) * sc0.x + sh0.x;
        o[1] = bf2f(v[1]) * sc0.y + sh0.y;
        o[2] = bf2f(v[2]) * sc0.z + sh0.z;
        o[3] = bf2f(v[3]) * sc0.w + sh0.w;
        o[4] = bf2f(v[4]) * sc1.x + sh1.x;
        o[5] = bf2f(v[5]) * sc1.y + sh1.y;
        o[6] = bf2f(v[6]) * sc1.z + sh1.z;
        o[7] = bf2f(v[7]) * sc1.w + sh1.w;
    }
    __syncthreads();

    float wv[Pdim][Fdim];
#pragma unroll
    for (int p = 0; p < Pdim; ++p)
#pragma unroll
        for (int f = 0; f < Fdim; ++f) wv[p][f] = wsm[p * Fdim + f];

    const float L2E = 1.44269504f;
    const float LN2 = 0.69314718f;

#pragma unroll
    for (int k = 0; k < 8; ++k) {
        const int idx = k * 256 + tid;
        int c, g = 0, q = 0;
        if (MODE == 0) { g = idx >> 9; q = idx & 511; c = q * 4 + g; }
        else           { c = idx; }

#pragma unroll
        for (int p = 0; p < Pdim; ++p) {
            const int2 jj = *(const int2*)(perm + p * Mdim + 2 * c);
            const float z0 = yn[jj.x];
            const float z1 = yn[jj.y];

            const float mx = fmaxf(z0, z1);
            const float pr = z0 * z1;
            const float a1 = copysignf(__builtin_amdgcn_sqrtf(fabsf(pr) + 1e-12f), pr);

            const float e0 = __builtin_amdgcn_exp2f(-L2E * z0);
            const float e1 = __builtin_amdgcn_exp2f(-L2E * z1);
            const float a2 = z0 * __builtin_amdgcn_rcpf((1.f + e0) * (1.f + e1));

            const float a3 = __builtin_amdgcn_sqrtf(z0 * z0 + z1 * z1 + 1e-12f);
            const float a4 = fmaxf(fabsf(z0), fabsf(z1));

            const float ed = __builtin_amdgcn_exp2f(-L2E * fabsf(z0 - z1));
            const float a5 = mx + LN2 * __builtin_amdgcn_logf(1.f + ed);

            const float v = wv[p][0] * mx + wv[p][1] * a1 + wv[p][2] * a2 +
                            wv[p][3] * a3 + wv[p][4] * a4 + wv[p][5] * a5;

            if (MODE == 0)
                out[(size_t)g * ((size_t)Bdim * CIN) + (size_t)b * CIN + p * 512 + q] = f2bf(v);
            else
                out[(size_t)b * DNEXT + p * CH + c] = f2bf(v);
        }
    }
}

// ---------------------------------------------------------------------------
extern "C" void kernel_launch(void* const* d_in, const int* in_sizes, int n_in,
                              void* d_out, int out_size, void* d_ws, size_t ws_size,
                              hipStream_t stream)
{
    const float* x     = (const float*)d_in[0];
    const int*   perms = (const int*)  d_in[1];
    const float* W     = (const float*)d_in[2];
    const float* bvec  = (const float*)d_in[3];
    const float* gamma = (const float*)d_in[4];
    const float* beta  = (const float*)d_in[5];
    const float* alpha = (const float*)d_in[6];
    const float* Wo    = (const float*)d_in[7];
    const float* bo    = (const float*)d_in[8];
    float* out = (float*)d_out;

    char* ws = (char*)d_ws;
    short* y      = (short*)ws;                             // B*M bf16 (grouped cols)
    short* hg     = y + (size_t)Bdim * Mdim;                // G*B*CIN bf16
    short* hflat  = hg + (size_t)Gdim * Bdim * CIN;         // B*8192 bf16
    short* Wlb    = hflat + (size_t)Bdim * DNEXT;           // G*MG*CIN bf16
    short* Wob    = Wlb + (size_t)Gdim * MG * CIN;          // 1024*8192 bf16
    float* psum   = (float*)(Wob + (size_t)1024 * DNEXT);
    float* psumsq = psum + (size_t)NRCHUNK * Mdim;
    float* scale  = psumsq + (size_t)NRCHUNK * Mdim;
    float* shift  = scale + Mdim;
    float* wsm    = shift + Mdim;
    int*   perm_g = (int*)(wsm + Lnum * Pdim * Fdim);       // L*P*M ints

    float* part = (float*)hg;   // 4 x (B*1024) f32 = 32 MB; hg dead by out-GEMM

    alpha_softmax<<<1, 64, 0, stream>>>(alpha, wsm);
    remap_perms<<<(Lnum * Pdim * Mdim) / 256, 256, 0, stream>>>(
        perms, perm_g, Lnum * Pdim * Mdim);
    convert_wo<<<(1024 * 1024) / 256, 256, 0, stream>>>(Wo, Wob);
    x_to_grouped<<<dim3(CIN / 256, Bdim), 256, 0, stream>>>(x, hg);

    const size_t planeA = (size_t)Bdim * CIN;
    const size_t planeB = (size_t)MG * CIN;

    for (int l = 0; l < Lnum; ++l) {
        convert_f32_bf16<<<(Gdim * MG * CIN / 8) / 256, 256, 0, stream>>>(
            W + (size_t)l * Gdim * MG * CIN, Wlb, Gdim * MG * CIN / 8);

        // y[b][g*1024+m] bf16, contiguous stores; BN partial stats fused.
        dim3 gg(MG / 128, Bdim / 128, Gdim);
        gemm_mfma<128, 8, true, short><<<gg, 512, 0, stream>>>(
            hg, planeA, CIN, Wlb, planeB, CIN,
            bvec + (size_t)l * Gdim * MG, (size_t)MG,
            y, (size_t)MG,
            CIN, Mdim, MG,
            psum, psumsq, MG);

        bn_finalize<<<Mdim / 256, 256, 0, stream>>>(
            psum, psumsq, gamma + (size_t)l * Mdim, beta + (size_t)l * Mdim, scale, shift);

        if (l < Lnum - 1)
            combinact_kernel<0><<<Bdim, 256, 0, stream>>>(
                y, scale, shift, perm_g + (size_t)l * Pdim * Mdim, wsm + l * Pdim * Fdim, hg);
        else
            combinact_kernel<1><<<Bdim, 256, 0, stream>>>(
                y, scale, shift, perm_g + (size_t)l * Pdim * Mdim, wsm + l * Pdim * Fdim, hflat);
    }

    // Output GEMM, split-K=4 (K=2048 each), partials in hg, then reduce.
    dim3 go(1024 / 128, Bdim / 128, 4);
    gemm_mfma<128, 8, false, float><<<go, 512, 0, stream>>>(
        hflat, (size_t)2048, DNEXT, Wob, (size_t)2048, DNEXT,
        nullptr, 0,
        part, (size_t)Bdim * 1024,
        2048, 1024, 1024,
        nullptr, nullptr, 0);

    dim3 gr(4, Bdim);
    reduce_out<<<gr, 256, 0, stream>>>(part, bo, out);
}

// Round 8
// 312.682 us; speedup vs baseline: 9.9418x; 1.0104x over previous
//
#include <hip/hip_runtime.h>
#include <math.h>

#define Lnum 3
#define Mdim 4096
#define Pdim 4
#define Gdim 4
#define NIN 8192
#define NOUT 1000
#define Bdim 2048
#define Fdim 6
#define CIN 2048      // input channels per group (all layers)
#define MG 1024       // M / G
#define CH 2048       // M / K
#define DNEXT 8192
#define NRCHUNK (Bdim / 128)   // 16 row-blocks of 128 = GEMM tile rows

typedef short bf16x8 __attribute__((ext_vector_type(8)));
typedef float f32x4 __attribute__((ext_vector_type(4)));

__device__ __forceinline__ short f2bf(float f) {
    union { float f; unsigned u; } v; v.f = f;
    unsigned u = v.u;
    unsigned r = (u + 0x7fffu + ((u >> 16) & 1u)) >> 16;
    return (short)r;
}
__device__ __forceinline__ float bf2f(short h) {
    union { unsigned u; float f; } x;
    x.u = ((unsigned)(unsigned short)h) << 16;
    return x.f;
}

// ---------------------------------------------------------------------------
__global__ __launch_bounds__(256) void convert_f32_bf16(
    const float* __restrict__ src, short* __restrict__ dst, int n8)
{
    int i = blockIdx.x * 256 + threadIdx.x;
    if (i >= n8) return;
    const float4* s = (const float4*)src + (size_t)i * 2;
    float4 v0 = s[0], v1 = s[1];
    bf16x8 o;
    o[0] = f2bf(v0.x); o[1] = f2bf(v0.y); o[2] = f2bf(v0.z); o[3] = f2bf(v0.w);
    o[4] = f2bf(v1.x); o[5] = f2bf(v1.y); o[6] = f2bf(v1.z); o[7] = f2bf(v1.w);
    *((bf16x8*)dst + i) = o;
}

// Wo (1000 x 8192) f32 -> padded (1024 x 8192) bf16, pad rows zero
__global__ __launch_bounds__(256) void convert_wo(
    const float* __restrict__ src, short* __restrict__ dst)
{
    int i = blockIdx.x * 256 + threadIdx.x;
    int row = i >> 10;
    bf16x8 o;
    if (row < NOUT) {
        const float4* s = (const float4*)(src + (size_t)row * DNEXT + (i & 1023) * 8);
        float4 v0 = s[0], v1 = s[1];
        o[0] = f2bf(v0.x); o[1] = f2bf(v0.y); o[2] = f2bf(v0.z); o[3] = f2bf(v0.w);
        o[4] = f2bf(v1.x); o[5] = f2bf(v1.y); o[6] = f2bf(v1.z); o[7] = f2bf(v1.w);
    } else {
        for (int j = 0; j < 8; ++j) o[j] = 0;
    }
    *((bf16x8*)dst + i) = o;
}

// x (B x 8192) f32 -> grouped bf16 planes hg[g][b][c] = x[b][4c+g]
__global__ __launch_bounds__(256) void x_to_grouped(
    const float* __restrict__ x, short* __restrict__ hg)
{
    const int c = blockIdx.x * 256 + threadIdx.x;
    const int b = blockIdx.y;
    float4 v = *(const float4*)(x + (size_t)b * NIN + 4 * c);
    const size_t plane = (size_t)Bdim * CIN;
    hg[0 * plane + (size_t)b * CIN + c] = f2bf(v.x);
    hg[1 * plane + (size_t)b * CIN + c] = f2bf(v.y);
    hg[2 * plane + (size_t)b * CIN + c] = f2bf(v.z);
    hg[3 * plane + (size_t)b * CIN + c] = f2bf(v.w);
}

// perm value remap into grouped-y coordinates: j -> (j&3)*1024 + (j>>2)
__global__ __launch_bounds__(256) void remap_perms(
    const int* __restrict__ perm, int* __restrict__ perm_g, int n)
{
    int i = blockIdx.x * 256 + threadIdx.x;
    if (i >= n) return;
    int j = perm[i];
    perm_g[i] = ((j & 3) << 10) | (j >> 2);
}

// ---------------------------------------------------------------------------
// MFMA bf16 GEMM, double-buffered, BK=64, XOR-swizzled LDS, counted vmcnt:
//   stage(next); vmcnt(4); barrier; compute(cur); barrier;
// keeps next-tile loads in flight across both barriers (2-deep pipeline).
// Tile 128 x BN_T, 8 waves (2x4). C[row,n] = A[row,:]·B[n,:]+bias.
// CT = short (bf16 store) or float. If STATS: per-column partial sum/sumsq ->
// psum/psumsq[by * Mdim + g*sgz + n0 + col] (deterministic, 1 writer/slot).
// ---------------------------------------------------------------------------
template<int BN_T, int NWARP, bool STATS, typename CT>
__global__ __launch_bounds__(NWARP * 64) void gemm_mfma(
    const short* __restrict__ A0, size_t aZ, int lda,
    const short* __restrict__ B0, size_t bZ, int ldb,
    const float* __restrict__ bias0, size_t biasZ,
    CT* __restrict__ C0, size_t cZ,
    int K, int ldc, int nbound,
    float* __restrict__ psum, float* __restrict__ psumsq, int sgz)
{
    constexpr int NT   = NWARP * 64;
    constexpr int WCN  = NWARP / 2;       // waves along N
    constexpr int WCOL = BN_T / WCN;      // cols per wave
    constexpr int FN   = WCOL / 16;       // 16-col frags per wave

    // XCD-aware swizzle (nwg % 8 == 0 in all our launches)
    const int nx = gridDim.x, ny = gridDim.y;
    const int nwg = nx * ny * gridDim.z;
    const int lin = blockIdx.x + nx * (blockIdx.y + ny * blockIdx.z);
    int swz = (lin & 7) * (nwg >> 3) + (lin >> 3);
    const int bx = swz % nx; swz /= nx;
    const int by = swz % ny;
    const int g  = swz / ny;

    const short* A  = A0 + aZ * g;
    const short* Bm = B0 + bZ * g;
    CT* C = C0 + cZ * g;

    const int n0 = bx * BN_T;
    const int b0 = by * 128;

    __shared__ short As[2][128 * 64];
    __shared__ short Bs[2][BN_T * 64];

    const int tid  = threadIdx.x;
    const int w    = tid >> 6;
    const int lane = tid & 63;
    const int wr = w / WCN, wc = w % WCN;

    f32x4 acc[4][FN];
#pragma unroll
    for (int m = 0; m < 4; ++m)
#pragma unroll
        for (int n = 0; n < FN; ++n) acc[m][n] = (f32x4)0.f;

    auto stage = [&](int buf, int k0) {
#pragma unroll
        for (int idx = tid; idx < 128 * 8; idx += NT) {
            const int r = idx >> 3, slot = idx & 7;
            const int gs = slot ^ (r & 7);
            const short* ga = A + (size_t)(b0 + r) * lda + k0 + gs * 8;
            __builtin_amdgcn_global_load_lds(
                (const __attribute__((address_space(1))) void*)ga,
                (__attribute__((address_space(3))) void*)(&As[buf][idx * 8]), 16, 0, 0);
        }
#pragma unroll
        for (int idx = tid; idx < BN_T * 8; idx += NT) {
            const int r = idx >> 3, slot = idx & 7;
            const int gs = slot ^ (r & 7);
            const short* gb = Bm + (size_t)(n0 + r) * ldb + k0 + gs * 8;
            __builtin_amdgcn_global_load_lds(
                (const __attribute__((address_space(1))) void*)gb,
                (__attribute__((address_space(3))) void*)(&Bs[buf][idx * 8]), 16, 0, 0);
        }
    };

    const int fr15 = lane & 15;
    const int fq   = lane >> 4;

    auto compute = [&](int buf) {
#pragma unroll
        for (int kk = 0; kk < 2; ++kk) {
            bf16x8 af[4], bff[FN];
            const int kob = kk * 64 + fq * 16;
#pragma unroll
            for (int m = 0; m < 4; ++m) {
                const int r  = wr * 64 + m * 16 + fr15;
                const int sw = kob ^ ((r & 7) << 4);
                af[m] = *(const bf16x8*)(&As[buf][r * 64 + (sw >> 1)]);
            }
#pragma unroll
            for (int n = 0; n < FN; ++n) {
                const int r  = wc * WCOL + n * 16 + fr15;
                const int sw = kob ^ ((r & 7) << 4);
                bff[n] = *(const bf16x8*)(&Bs[buf][r * 64 + (sw >> 1)]);
            }
#pragma unroll
            for (int m = 0; m < 4; ++m)
#pragma unroll
                for (int n = 0; n < FN; ++n)
                    acc[m][n] = __builtin_amdgcn_mfma_f32_16x16x32_bf16(af[m], bff[n], acc[m][n], 0, 0, 0);
        }
    };

    // Prologue: stage tile 0.
    stage(0, 0);

    const int nt = K >> 6;   // always even here (K multiple of 128)
    int p = 0;
    for (int t = 0; t < nt - 1; ++t) {
        stage(p ^ 1, (t + 1) << 6);
        // wait only for buf[p]'s 4 loads (issued last iteration); the 4 just
        // issued for buf[p^1] stay in flight across both barriers.
        asm volatile("s_waitcnt vmcnt(4)" ::: "memory");
        __builtin_amdgcn_s_barrier();
        asm volatile("" ::: "memory");
        compute(p);
        asm volatile("" ::: "memory");
        __builtin_amdgcn_s_barrier();
        p ^= 1;
    }
    asm volatile("s_waitcnt vmcnt(0)" ::: "memory");
    __builtin_amdgcn_s_barrier();
    asm volatile("" ::: "memory");
    compute(p);

    float s[FN], ss[FN];
#pragma unroll
    for (int n = 0; n < FN; ++n) { s[n] = 0.f; ss[n] = 0.f; }

#pragma unroll
    for (int m = 0; m < 4; ++m) {
#pragma unroll
        for (int n = 0; n < FN; ++n) {
#pragma unroll
            for (int j = 0; j < 4; ++j) {
                const int row = b0 + wr * 64 + m * 16 + fq * 4 + j;
                const int col = n0 + wc * WCOL + n * 16 + fr15;
                if (col < nbound) {
                    float v = acc[m][n][j];
                    if (bias0) v += bias0[biasZ * g + col];
                    C[(size_t)row * ldc + col] = (CT)(sizeof(CT) == 2 ? (CT)f2bf(v) : (CT)v);
                    if (STATS) { s[n] += v; ss[n] += v * v; }
                }
            }
        }
    }

    if (STATS) {
        __syncthreads();   // all waves done with LDS compute buffers
        float* sum_lds = (float*)&As[0][0];
        float* ssq_lds = sum_lds + BN_T * 8;
        const int slot = wr * 4 + fq;
#pragma unroll
        for (int n = 0; n < FN; ++n) {
            const int cl = wc * WCOL + n * 16 + fr15;
            sum_lds[cl * 8 + slot] = s[n];
            ssq_lds[cl * 8 + slot] = ss[n];
        }
        __syncthreads();
        for (int cl = tid; cl < BN_T; cl += NT) {
            float a = 0.f, b = 0.f;
#pragma unroll
            for (int q = 0; q < 8; ++q) {
                a += sum_lds[cl * 8 + q];
                b += ssq_lds[cl * 8 + q];
            }
            const size_t o = (size_t)by * Mdim + g * sgz + n0 + cl;
            psum[o]   = a;
            psumsq[o] = b;
        }
    }
}

// out[b,n] = sum_z p[z][b,n] + bo[n], 4 split-K partials
__global__ __launch_bounds__(256) void reduce_out(
    const float* __restrict__ part, const float* __restrict__ bo,
    float* __restrict__ out)
{
    const int n = blockIdx.x * 256 + threadIdx.x;
    const int b = blockIdx.y;
    if (n >= NOUT) return;
    const size_t S = (size_t)Bdim * 1024;
    const size_t i = (size_t)b * 1024 + n;
    out[(size_t)b * NOUT + n] =
        part[i] + part[S + i] + part[2 * S + i] + part[3 * S + i] + bo[n];
}

// ---------------------------------------------------------------------------
// Columns are in GROUPED order jg = g*1024+m  (orig j = (jg&1023)*4 + jg>>10)
__global__ __launch_bounds__(256) void bn_finalize(
    const float* __restrict__ psum, const float* __restrict__ psumsq,
    const float* __restrict__ gamma, const float* __restrict__ beta,
    float* __restrict__ scale, float* __restrict__ shift)
{
    const int jg = blockIdx.x * 256 + threadIdx.x;
    if (jg >= Mdim) return;
    const int j = ((jg & 1023) << 2) | (jg >> 10);
    float s = 0.f, ss = 0.f;
    for (int r = 0; r < NRCHUNK; ++r) {
        s  += psum[r * Mdim + jg];
        ss += psumsq[r * Mdim + jg];
    }
    const float mu  = s * (1.f / Bdim);
    const float var = ss * (1.f / Bdim) - mu * mu;
    const float sc  = gamma[j] * rsqrtf(var + 1e-5f);
    scale[jg] = sc;
    shift[jg] = beta[j] - mu * sc;
}

__global__ void alpha_softmax(const float* __restrict__ alpha, float* __restrict__ wsm)
{
    const int idx = threadIdx.x;
    if (idx >= Lnum * Pdim) return;
    const float* a = alpha + idx * Fdim;
    float mx = a[0];
#pragma unroll
    for (int f = 1; f < Fdim; ++f) mx = fmaxf(mx, a[f]);
    float e[Fdim]; float s = 0.f;
#pragma unroll
    for (int f = 0; f < Fdim; ++f) { e[f] = __expf(a[f] - mx); s += e[f]; }
    const float inv = 1.f / s;
#pragma unroll
    for (int f = 0; f < Fdim; ++f) wsm[idx * Fdim + f] = e[f] * inv;
}

// ---------------------------------------------------------------------------
// Fused normalize + permutation gather + combinact (K=2 closed form).
// Y is bf16 in grouped layout; perm holds pre-remapped (grouped) indices.
// MODE 0: grouped planes hg[g][b][p*512+q], c=q*4+g ; MODE 1: flat h[b][p*CH+c]
// ---------------------------------------------------------------------------
template<int MODE>
__global__ __launch_bounds__(256) void combinact_kernel(
    const short* __restrict__ Y, const float* __restrict__ scale,
    const float* __restrict__ shift, const int* __restrict__ perm,
    const float* __restrict__ wsm, short* __restrict__ out)
{
    __shared__ float yn[Mdim];
    const int b   = blockIdx.x;
    const int tid = threadIdx.x;

#pragma unroll
    for (int k = 0; k < 2; ++k) {
        const int i8 = k * 256 + tid;           // 512 chunks of 8
        bf16x8 v = *((const bf16x8*)(Y + (size_t)b * Mdim) + i8);
        float4 sc0 = *(const float4*)(scale + i8 * 8);
        float4 sc1 = *(const float4*)(scale + i8 * 8 + 4);
        float4 sh0 = *(const float4*)(shift + i8 * 8);
        float4 sh1 = *(const float4*)(shift + i8 * 8 + 4);
        float* o = yn + i8 * 8;
        o[0] = bf2f(v[0]) * sc0.x + sh0.x;
        o[1] = bf2f(v[1]) * sc0.y + sh0.y;
        o[2] = bf2f(v[2]) * sc0.z + sh0.z;
        o[3] = bf2f(v[3]) * sc0.w + sh0.w;
        o[4] = bf2f(v[4]) * sc1.x + sh1.x;
        o[5] = bf2f(v[5]) * sc1.y + sh1.y;
        o[6] = bf2f(v[6]) * sc1.z + sh1.z;
        o[7] = bf2f(v[7]) * sc1.w + sh1.w;
    }
    __syncthreads();

    float wv[Pdim][Fdim];
#pragma unroll
    for (int p = 0; p < Pdim; ++p)
#pragma unroll
        for (int f = 0; f < Fdim; ++f) wv[p][f] = wsm[p * Fdim + f];

    const float L2E = 1.44269504f;
    const float LN2 = 0.69314718f;

#pragma unroll
    for (int k = 0; k < 8; ++k) {
        const int idx = k * 256 + tid;
        int c, g = 0, q = 0;
        if (MODE == 0) { g = idx >> 9; q = idx & 511; c = q * 4 + g; }
        else           { c = idx; }

#pragma unroll
        for (int p = 0; p < Pdim; ++p) {
            const int2 jj = *(const int2*)(perm + p * Mdim + 2 * c);
            const float z0 = yn[jj.x];
            const float z1 = yn[jj.y];

            const float mx = fmaxf(z0, z1);
            const float pr = z0 * z1;
            const float a1 = copysignf(__builtin_amdgcn_sqrtf(fabsf(pr) + 1e-12f), pr);

            const float e0 = __builtin_amdgcn_exp2f(-L2E * z0);
            const float e1 = __builtin_amdgcn_exp2f(-L2E * z1);
            const float a2 = z0 * __builtin_amdgcn_rcpf((1.f + e0) * (1.f + e1));

            const float a3 = __builtin_amdgcn_sqrtf(z0 * z0 + z1 * z1 + 1e-12f);
            const float a4 = fmaxf(fabsf(z0), fabsf(z1));

            const float ed = __builtin_amdgcn_exp2f(-L2E * fabsf(z0 - z1));
            const float a5 = mx + LN2 * __builtin_amdgcn_logf(1.f + ed);

            const float v = wv[p][0] * mx + wv[p][1] * a1 + wv[p][2] * a2 +
                            wv[p][3] * a3 + wv[p][4] * a4 + wv[p][5] * a5;

            if (MODE == 0)
                out[(size_t)g * ((size_t)Bdim * CIN) + (size_t)b * CIN + p * 512 + q] = f2bf(v);
            else
                out[(size_t)b * DNEXT + p * CH + c] = f2bf(v);
        }
    }
}

// ---------------------------------------------------------------------------
extern "C" void kernel_launch(void* const* d_in, const int* in_sizes, int n_in,
                              void* d_out, int out_size, void* d_ws, size_t ws_size,
                              hipStream_t stream)
{
    const float* x     = (const float*)d_in[0];
    const int*   perms = (const int*)  d_in[1];
    const float* W     = (const float*)d_in[2];
    const float* bvec  = (const float*)d_in[3];
    const float* gamma = (const float*)d_in[4];
    const float* beta  = (const float*)d_in[5];
    const float* alpha = (const float*)d_in[6];
    const float* Wo    = (const float*)d_in[7];
    const float* bo    = (const float*)d_in[8];
    float* out = (float*)d_out;

    char* ws = (char*)d_ws;
    short* y      = (short*)ws;                             // B*M bf16 (grouped cols)
    short* hg     = y + (size_t)Bdim * Mdim;                // G*B*CIN bf16 (also hflat)
    short* Wlb3   = hg + (size_t)Gdim * Bdim * CIN;         // 3*G*MG*CIN bf16 (all layers)
    short* Wob    = Wlb3 + (size_t)Lnum * Gdim * MG * CIN;  // 1024*8192 bf16
    float* psum   = (float*)(Wob + (size_t)1024 * DNEXT);
    float* psumsq = psum + (size_t)NRCHUNK * Mdim;
    float* scale  = psumsq + (size_t)NRCHUNK * Mdim;
    float* shift  = scale + Mdim;
    float* wsm    = shift + Mdim;
    int*   perm_g = (int*)(wsm + Lnum * Pdim * Fdim);       // L*P*M ints

    short* hflat = hg;           // layer-2 combinact output aliases hg (dead then)
    float* part  = (float*)Wlb3; // out-GEMM partials alias Wlb3 (dead then), 32 MB

    alpha_softmax<<<1, 64, 0, stream>>>(alpha, wsm);
    remap_perms<<<(Lnum * Pdim * Mdim) / 256, 256, 0, stream>>>(
        perms, perm_g, Lnum * Pdim * Mdim);
    // all three layers' W at once (contiguous), plus Wo and x regroup
    convert_f32_bf16<<<(Lnum * Gdim * MG * CIN / 8) / 256, 256, 0, stream>>>(
        W, Wlb3, Lnum * Gdim * MG * CIN / 8);
    convert_wo<<<(1024 * 1024) / 256, 256, 0, stream>>>(Wo, Wob);
    x_to_grouped<<<dim3(CIN / 256, Bdim), 256, 0, stream>>>(x, hg);

    const size_t planeA = (size_t)Bdim * CIN;
    const size_t planeB = (size_t)MG * CIN;

    for (int l = 0; l < Lnum; ++l) {
        // y[b][g*1024+m] bf16, contiguous stores; BN partial stats fused.
        dim3 gg(MG / 128, Bdim / 128, Gdim);
        gemm_mfma<128, 8, true, short><<<gg, 512, 0, stream>>>(
            hg, planeA, CIN, Wlb3 + (size_t)l * Gdim * MG * CIN, planeB, CIN,
            bvec + (size_t)l * Gdim * MG, (size_t)MG,
            y, (size_t)MG,
            CIN, Mdim, MG,
            psum, psumsq, MG);

        bn_finalize<<<Mdim / 256, 256, 0, stream>>>(
            psum, psumsq, gamma + (size_t)l * Mdim, beta + (size_t)l * Mdim, scale, shift);

        if (l < Lnum - 1)
            combinact_kernel<0><<<Bdim, 256, 0, stream>>>(
                y, scale, shift, perm_g + (size_t)l * Pdim * Mdim, wsm + l * Pdim * Fdim, hg);
        else
            combinact_kernel<1><<<Bdim, 256, 0, stream>>>(
                y, scale, shift, perm_g + (size_t)l * Pdim * Mdim, wsm + l * Pdim * Fdim, hflat);
    }

    // Output GEMM, split-K=4 (K=2048 each), partials in Wlb3 region, then reduce.
    dim3 go(1024 / 128, Bdim / 128, 4);
    gemm_mfma<128, 8, false, float><<<go, 512, 0, stream>>>(
        hflat, (size_t)2048, DNEXT, Wob, (size_t)2048, DNEXT,
        nullptr, 0,
        part, (size_t)Bdim * 1024,
        2048, 1024, 1024,
        nullptr, nullptr, 0);

    dim3 gr(4, Bdim);
    reduce_out<<<gr, 256, 0, stream>>>(part, bo, out);
}